// Round 2
// baseline (1249.054 us; speedup 1.0000x reference)
//
#include <hip/hip_runtime.h>
#include <math.h>

#define NB 16
#define NN 1024
#define ND 128
#define NH 8
#define DH 16

static __device__ __forceinline__ float dot4(float4 a, float4 b) {
  return a.x * b.x + a.y * b.y + a.z * b.z + a.w * b.w;
}

// ---------------- Kernel 1: SineEncoding + eig linear ----------------
__global__ __launch_bounds__(128) void k_sine_eig(
    const float* __restrict__ eva, const float* __restrict__ W,
    const float* __restrict__ bias, float* __restrict__ eig) {
  int bn = blockIdx.x, t = threadIdx.x;
  __shared__ float ee[129];
  float e = eva[bn];
  if (t == 0) ee[0] = e;
  if (t < 64) {
    // div = exp(2t * (-ln(10000)/128))
    float div = expf((float)(2 * t) * (-9.210340371976184f / 128.0f));
    float pe = e * 100.0f * div;
    ee[1 + t] = sinf(pe);
    ee[65 + t] = cosf(pe);
  }
  __syncthreads();
  const float* wr = W + t * 129;
  float acc = bias[t];
  for (int j = 0; j < 129; ++j) acc += ee[j] * wr[j];
  eig[bn * ND + t] = acc;
}

// ---------------- Kernel 2: LN1 + QKV projection ----------------
__global__ __launch_bounds__(128) void k_ln_qkv(
    const float* __restrict__ eig, const float* __restrict__ gs,
    const float* __restrict__ gb, const float* __restrict__ W,
    const float* __restrict__ wb, float* __restrict__ qg,
    float* __restrict__ kg, float* __restrict__ vg) {
  int bn = blockIdx.x, t = threadIdx.x;
  __shared__ float red[128];
  __shared__ float hbuf[128];
  float x = eig[bn * ND + t];
  red[t] = x;
  __syncthreads();
#pragma unroll
  for (int off = 64; off > 0; off >>= 1) {
    if (t < off) red[t] += red[t + off];
    __syncthreads();
  }
  float mean = red[0] * (1.0f / 128.0f);
  __syncthreads();
  float xc = x - mean;
  red[t] = xc * xc;
  __syncthreads();
#pragma unroll
  for (int off = 64; off > 0; off >>= 1) {
    if (t < off) red[t] += red[t + off];
    __syncthreads();
  }
  float var = red[0] * (1.0f / 128.0f);
  hbuf[t] = xc * rsqrtf(var + 1e-5f) * gs[t] + gb[t];
  __syncthreads();
  const float4* h4 = (const float4*)hbuf;
#pragma unroll
  for (int r = 0; r < 3; ++r) {
    int row = r * 128 + t;
    const float4* wr = (const float4*)(W + row * ND);
    float acc = wb[row];
#pragma unroll 8
    for (int e = 0; e < 32; ++e) acc += dot4(h4[e], wr[e]);
    (r == 0 ? qg : r == 1 ? kg : vg)[bn * ND + t] = acc;
  }
}

// ---------------- Kernel 3: flash-style attention ----------------
// one thread = one query row; K/V tiles staged in LDS
__global__ __launch_bounds__(256) void k_attn(
    const float* __restrict__ qg, const float* __restrict__ kg,
    const float* __restrict__ vg, const int* __restrict__ length,
    float* __restrict__ att) {
  __shared__ float Kt[128 * DH];
  __shared__ float Vt[128 * DH];
  int blk = blockIdx.x;
  int bb = blk >> 5;  // / (H * N/256) = /32
  int rem = blk & 31;
  int hh = rem >> 2;
  int qt = rem & 3;
  int qi = qt * 256 + threadIdx.x;
  int len = length[bb];
  const float* qrow = qg + (bb * NN + qi) * ND + hh * DH;
  float4 q0 = ((const float4*)qrow)[0];
  float4 q1 = ((const float4*)qrow)[1];
  float4 q2 = ((const float4*)qrow)[2];
  float4 q3 = ((const float4*)qrow)[3];
  float4 o0 = {0, 0, 0, 0}, o1 = {0, 0, 0, 0}, o2 = {0, 0, 0, 0},
         o3 = {0, 0, 0, 0};
  float m = -INFINITY, l = 0.f;
  for (int t0 = 0; t0 < NN; t0 += 128) {
    const float* kb = kg + (bb * NN + t0) * ND + hh * DH;
    const float* vb = vg + (bb * NN + t0) * ND + hh * DH;
#pragma unroll
    for (int f = threadIdx.x; f < 512; f += 256) {
      int j = f >> 2, c = f & 3;
      ((float4*)Kt)[f] = ((const float4*)(kb + j * ND))[c];
      ((float4*)Vt)[f] = ((const float4*)(vb + j * ND))[c];
    }
    __syncthreads();
    for (int j = 0; j < 128; ++j) {
      const float4* kr = ((const float4*)Kt) + j * 4;
      float s = dot4(q0, kr[0]) + dot4(q1, kr[1]) + dot4(q2, kr[2]) +
                dot4(q3, kr[3]);
      int jg = t0 + j;
      float sc = (jg < len) ? s * 0.25f : -1e9f;
      float mn = fmaxf(m, sc);
      float corr = __expf(m - mn);
      float p = __expf(sc - mn);
      l = l * corr + p;
      const float4* vr = ((const float4*)Vt) + j * 4;
      float4 va = vr[0], vb4 = vr[1], vc4 = vr[2], vd4 = vr[3];
      o0.x = o0.x * corr + p * va.x;
      o0.y = o0.y * corr + p * va.y;
      o0.z = o0.z * corr + p * va.z;
      o0.w = o0.w * corr + p * va.w;
      o1.x = o1.x * corr + p * vb4.x;
      o1.y = o1.y * corr + p * vb4.y;
      o1.z = o1.z * corr + p * vb4.z;
      o1.w = o1.w * corr + p * vb4.w;
      o2.x = o2.x * corr + p * vc4.x;
      o2.y = o2.y * corr + p * vc4.y;
      o2.z = o2.z * corr + p * vc4.z;
      o2.w = o2.w * corr + p * vc4.w;
      o3.x = o3.x * corr + p * vd4.x;
      o3.y = o3.y * corr + p * vd4.y;
      o3.z = o3.z * corr + p * vd4.z;
      o3.w = o3.w * corr + p * vd4.w;
      m = mn;
    }
    __syncthreads();
  }
  float inv = 1.0f / l;
  float* orow = att + (bb * NN + qi) * ND + hh * DH;
  ((float4*)orow)[0] = make_float4(o0.x * inv, o0.y * inv, o0.z * inv, o0.w * inv);
  ((float4*)orow)[1] = make_float4(o1.x * inv, o1.y * inv, o1.z * inv, o1.w * inv);
  ((float4*)orow)[2] = make_float4(o2.x * inv, o2.y * inv, o2.z * inv, o2.w * inv);
  ((float4*)orow)[3] = make_float4(o3.x * inv, o3.y * inv, o3.z * inv, o3.w * inv);
}

// ---------------- Kernel 4: out-projection + residual ----------------
__global__ __launch_bounds__(128) void k_outproj(
    const float* __restrict__ att, const float* __restrict__ W,
    const float* __restrict__ ob, float* __restrict__ eig) {
  int bn = blockIdx.x, t = threadIdx.x;
  __shared__ float abuf[128];
  abuf[t] = att[bn * ND + t];
  __syncthreads();
  const float4* a4 = (const float4*)abuf;
  const float4* wr = (const float4*)(W + t * ND);
  float acc = ob[t];
#pragma unroll 8
  for (int e = 0; e < 32; ++e) acc += dot4(a4[e], wr[e]);
  eig[bn * ND + t] += acc;
}

// ---------------- Kernel 5: LN2 + FFN (gelu) + residual ----------------
__global__ __launch_bounds__(128) void k_ffn(
    float* __restrict__ eig, const float* __restrict__ gs,
    const float* __restrict__ gb, const float* __restrict__ W1,
    const float* __restrict__ b1, const float* __restrict__ W2,
    const float* __restrict__ b2) {
  int bn = blockIdx.x, t = threadIdx.x;
  __shared__ float red[128];
  __shared__ float hbuf[128];
  __shared__ float fbuf[128];
  float x = eig[bn * ND + t];
  red[t] = x;
  __syncthreads();
#pragma unroll
  for (int off = 64; off > 0; off >>= 1) {
    if (t < off) red[t] += red[t + off];
    __syncthreads();
  }
  float mean = red[0] * (1.0f / 128.0f);
  __syncthreads();
  float xc = x - mean;
  red[t] = xc * xc;
  __syncthreads();
#pragma unroll
  for (int off = 64; off > 0; off >>= 1) {
    if (t < off) red[t] += red[t + off];
    __syncthreads();
  }
  float var = red[0] * (1.0f / 128.0f);
  hbuf[t] = xc * rsqrtf(var + 1e-5f) * gs[t] + gb[t];
  __syncthreads();
  const float4* h4 = (const float4*)hbuf;
  const float4* w1r = (const float4*)(W1 + t * ND);
  float acc = b1[t];
#pragma unroll 8
  for (int e = 0; e < 32; ++e) acc += dot4(h4[e], w1r[e]);
  float g = acc;
  fbuf[t] = 0.5f * g * (1.0f + erff(g * 0.7071067811865475f));
  __syncthreads();
  const float4* f4 = (const float4*)fbuf;
  const float4* w2r = (const float4*)(W2 + t * ND);
  float acc2 = b2[t];
#pragma unroll 8
  for (int e = 0; e < 32; ++e) acc2 += dot4(f4[e], w2r[e]);
  eig[bn * ND + t] = x + acc2;
}

// ---------------- Kernel 6: masked mean-pool for 3 decoders ----------------
// 20 channels: 0..7 sca, 8..15 wav, 16..19 scl
__global__ __launch_bounds__(256) void k_pool(
    const float* __restrict__ eig, const int* __restrict__ length,
    const float* __restrict__ dsW, const float* __restrict__ dsB,
    const float* __restrict__ dwW, const float* __restrict__ dwB,
    const float* __restrict__ dlW, const float* __restrict__ dlB,
    float* __restrict__ pooled) {
  int b = blockIdx.x, t = threadIdx.x;
  __shared__ float Ws[20][128];
  __shared__ float wred[4][20];
  for (int i = t; i < 2560; i += 256) {
    int c = i >> 7, e = i & 127;
    Ws[c][e] = c < 8 ? dsW[c * 128 + e]
                     : (c < 16 ? dwW[(c - 8) * 128 + e] : dlW[(c - 16) * 128 + e]);
  }
  __syncthreads();
  int len = length[b];
  float part[20];
#pragma unroll
  for (int c = 0; c < 20; ++c) part[c] = 0.f;
  for (int n = t; n < len; n += 256) {
    const float4* row = (const float4*)(eig + (b * NN + n) * ND);
    for (int e4 = 0; e4 < 32; ++e4) {
      float4 x = row[e4];
#pragma unroll
      for (int c = 0; c < 20; ++c) {
        part[c] += x.x * Ws[c][e4 * 4] + x.y * Ws[c][e4 * 4 + 1] +
                   x.z * Ws[c][e4 * 4 + 2] + x.w * Ws[c][e4 * 4 + 3];
      }
    }
  }
  int lane = t & 63, w = t >> 6;
#pragma unroll
  for (int c = 0; c < 20; ++c) {
    float vsum = part[c];
    for (int off = 32; off > 0; off >>= 1) vsum += __shfl_down(vsum, off, 64);
    if (lane == 0) wred[w][c] = vsum;
  }
  __syncthreads();
  if (t < 20) {
    float S = wred[0][t] + wred[1][t] + wred[2][t] + wred[3][t];
    float bias = t < 8 ? dsB[t] : (t < 16 ? dwB[t - 8] : dlB[t - 16]);
    float lf = (float)len;
    pooled[b * 20 + t] = (S + lf * bias) / (lf + 1e-8f);
  }
}

// ---------------- Kernel 7: sigmoid + normalize coefficients ----------------
__global__ void k_coe(const float* __restrict__ pooled, float* __restrict__ coe) {
  int b = blockIdx.x;
  if (threadIdx.x == 0) {
    float sg[20];
    for (int i = 0; i < 20; ++i) sg[i] = 1.f / (1.f + expf(-pooled[b * 20 + i]));
    float s1 = 0.f, s2 = 0.f;
    for (int i = 0; i < 8; ++i) s1 += sg[i];
    for (int i = 8; i < 16; ++i) s2 += sg[i];
    for (int i = 0; i < 8; ++i) coe[b * 20 + i] = sg[i] / (s1 + 1e-8f);
    for (int i = 0; i < 8; ++i) coe[b * 20 + 8 + i] = sg[8 + i] / (s2 + 1e-8f);
    for (int j = 0; j < 4; ++j) coe[b * 20 + 16 + j] = sg[16 + j] * 2.0f;
  }
}

// ---------------- Kernel 8: Chebyshev wave synthesis + tight frame ----------------
__global__ __launch_bounds__(256) void k_wave(const float* __restrict__ eva,
                                              const float* __restrict__ coe,
                                              float* __restrict__ out) {
  int bn = blockIdx.x * 256 + threadIdx.x;  // < B*N
  int b = bn >> 10;
  float e = eva[bn];
  const float* cb = coe + b * 20;
  // scaling: sca list (odd terms), y = e - 1
  float y = e - 1.0f;
  float te = 1.0f, to = y;
  float cs = cb[0] * 0.5f * (1.0f - to);
#pragma unroll
  for (int i = 1; i < 8; ++i) {
    te = 2.f * y * to - te;
    to = 2.f * y * te - to;
    cs += cb[i] * 0.5f * (1.0f - to);
  }
  // wavelet: wav list (even terms), y = fsw - 1
  float cw[4];
#pragma unroll
  for (int j = 0; j < 4; ++j) {
    float fs = e * cb[16 + j];
    fs = (fs > 2.0f) ? 0.0f : fs;
    float yw = fs - 1.0f;
    float te2 = 1.0f, to2 = yw;
    float acc = cb[8] * 0.5f * (1.0f - te2);  // == 0, kept for exactness
#pragma unroll
    for (int i = 1; i < 8; ++i) {
      te2 = 2.f * yw * to2 - te2;
      to2 = 2.f * yw * te2 - to2;
      acc += cb[8 + i] * 0.5f * (1.0f - te2);
    }
    cw[j] = acc;
  }
  float nrm = cs * cs + cw[0] * cw[0] + cw[1] * cw[1] + cw[2] * cw[2] + cw[3] * cw[3];
  float inv = 1.0f / (sqrtf(nrm) + 1e-8f);
  float* o = out + bn * 5;
  o[0] = cs * inv;
  o[1] = cw[0] * inv;
  o[2] = cw[1] * inv;
  o[3] = cw[2] * inv;
  o[4] = cw[3] * inv;
}

extern "C" void kernel_launch(void* const* d_in, const int* in_sizes, int n_in,
                              void* d_out, int out_size, void* d_ws,
                              size_t ws_size, hipStream_t stream) {
  const float* eva = (const float*)d_in[1];      // [B,N]
  const int* length = (const int*)d_in[2];       // [B]
  const float* eig_w_W = (const float*)d_in[3];  // [128,129]
  const float* eig_w_b = (const float*)d_in[4];
  const float* ln1_s = (const float*)d_in[5];
  const float* ln1_b = (const float*)d_in[6];
  const float* ln2_s = (const float*)d_in[7];
  const float* ln2_b = (const float*)d_in[8];
  const float* qkv_W = (const float*)d_in[9];  // [384,128]
  const float* qkv_b = (const float*)d_in[10];
  const float* out_W = (const float*)d_in[11];  // [128,128]
  const float* out_b = (const float*)d_in[12];
  const float* ffn_W1 = (const float*)d_in[13];
  const float* ffn_b1 = (const float*)d_in[14];
  const float* ffn_W2 = (const float*)d_in[15];
  const float* ffn_b2 = (const float*)d_in[16];
  const float* dec_sca_W = (const float*)d_in[17];
  const float* dec_sca_b = (const float*)d_in[18];
  const float* dec_wav_W = (const float*)d_in[19];
  const float* dec_wav_b = (const float*)d_in[20];
  const float* dec_scl_W = (const float*)d_in[21];
  const float* dec_scl_b = (const float*)d_in[22];

  float* ws = (float*)d_ws;
  const int SZ = NB * NN * ND;  // 2097152
  float* eig = ws;
  float* q = ws + SZ;
  float* k = ws + 2 * SZ;
  float* v = ws + 3 * SZ;
  float* att = ws + 4 * SZ;
  float* pooled = ws + 5 * SZ;
  float* coe = pooled + 512;

  k_sine_eig<<<NB * NN, 128, 0, stream>>>(eva, eig_w_W, eig_w_b, eig);
  k_ln_qkv<<<NB * NN, 128, 0, stream>>>(eig, ln1_s, ln1_b, qkv_W, qkv_b, q, k, v);
  k_attn<<<NB * NH * (NN / 256), 256, 0, stream>>>(q, k, v, length, att);
  k_outproj<<<NB * NN, 128, 0, stream>>>(att, out_W, out_b, eig);
  k_ffn<<<NB * NN, 128, 0, stream>>>(eig, ln2_s, ln2_b, ffn_W1, ffn_b1, ffn_W2, ffn_b2);
  k_pool<<<NB, 256, 0, stream>>>(eig, length, dec_sca_W, dec_sca_b, dec_wav_W,
                                 dec_wav_b, dec_scl_W, dec_scl_b, pooled);
  k_coe<<<NB, 32, 0, stream>>>(pooled, coe);
  k_wave<<<(NB * NN) / 256, 256, 0, stream>>>(eva, coe, (float*)d_out);
}

// Round 3
// 335.514 us; speedup vs baseline: 3.7228x; 3.7228x over previous
//
#include <hip/hip_runtime.h>
#include <math.h>

#define NB 16
#define NN 1024
#define ND 128
#define NH 8
#define DH 16

static __device__ __forceinline__ float dot4(float4 a, float4 b) {
  return a.x * b.x + a.y * b.y + a.z * b.z + a.w * b.w;
}

// reduce 8 per-thread values across a 128-thread block (2 waves)
static __device__ __forceinline__ void row8_reduce(const float v[8], float out[8],
                                                   float (*scr)[2], int t) {
  int lane = t & 63, w = t >> 6;
#pragma unroll
  for (int r = 0; r < 8; ++r) {
    float x = v[r];
#pragma unroll
    for (int off = 32; off > 0; off >>= 1) x += __shfl_down(x, off, 64);
    if (lane == 0) scr[r][w] = x;
  }
  __syncthreads();
#pragma unroll
  for (int r = 0; r < 8; ++r) out[r] = scr[r][0] + scr[r][1];
}

// ---------- Kernel A: sine-encoding + eig linear + LN1 + QKV (8 rows/block) ----------
__global__ __launch_bounds__(128) void kA(
    const float* __restrict__ eva, const float* __restrict__ eW,
    const float* __restrict__ eb, const float* __restrict__ g1s,
    const float* __restrict__ g1b, const float* __restrict__ qW,
    const float* __restrict__ qb, float* __restrict__ eig,
    float* __restrict__ qg, float* __restrict__ kg, float* __restrict__ vg) {
  __shared__ __align__(16) float ee[8][132];
  __shared__ __align__(16) float hb[8][128];
  __shared__ float scrA[8][2], scrB[8][2];
  int t = threadIdx.x;
  int rows0 = blockIdx.x * 8;
  int d = t & 63;
  float div = expf((float)(2 * d) * (-9.210340371976184f / 128.0f));
#pragma unroll
  for (int r = 0; r < 8; ++r) {
    float e = eva[rows0 + r];
    if (t == 0) ee[r][0] = e;
    float pe = e * 100.0f * div;
    if (t < 64) ee[r][1 + d] = sinf(pe);
    else ee[r][65 + d] = cosf(pe);
  }
  __syncthreads();
  float acc[8];
#pragma unroll
  for (int r = 0; r < 8; ++r) acc[r] = eb[t];
  const float* wr = eW + t * 129;
#pragma unroll 4
  for (int j4 = 0; j4 < 32; ++j4) {
    float w0 = wr[j4 * 4], w1 = wr[j4 * 4 + 1], w2 = wr[j4 * 4 + 2],
          w3 = wr[j4 * 4 + 3];
#pragma unroll
    for (int r = 0; r < 8; ++r) {
      float4 ev = *(const float4*)&ee[r][j4 * 4];
      acc[r] += ev.x * w0 + ev.y * w1 + ev.z * w2 + ev.w * w3;
    }
  }
  {
    float w = wr[128];
#pragma unroll
    for (int r = 0; r < 8; ++r) acc[r] += ee[r][128] * w;
  }
#pragma unroll
  for (int r = 0; r < 8; ++r) eig[(rows0 + r) * ND + t] = acc[r];
  // LN1
  float ms[8];
  row8_reduce(acc, ms, scrA, t);
  float xc[8], sq[8];
#pragma unroll
  for (int r = 0; r < 8; ++r) {
    xc[r] = acc[r] - ms[r] * (1.0f / 128.0f);
    sq[r] = xc[r] * xc[r];
  }
  float vs[8];
  row8_reduce(sq, vs, scrB, t);
  float s1 = g1s[t], b1v = g1b[t];
#pragma unroll
  for (int r = 0; r < 8; ++r)
    hb[r][t] = xc[r] * rsqrtf(vs[r] * (1.0f / 128.0f) + 1e-5f) * s1 + b1v;
  __syncthreads();
  // QKV
  float aq[8], ak[8], av[8];
  float bq = qb[t], bk = qb[128 + t], bv = qb[256 + t];
#pragma unroll
  for (int r = 0; r < 8; ++r) { aq[r] = bq; ak[r] = bk; av[r] = bv; }
  const float4* wq = (const float4*)(qW + t * 128);
  const float4* wk = (const float4*)(qW + (128 + t) * 128);
  const float4* wv = (const float4*)(qW + (256 + t) * 128);
#pragma unroll 4
  for (int j4 = 0; j4 < 32; ++j4) {
    float4 a = wq[j4], b = wk[j4], c = wv[j4];
#pragma unroll
    for (int r = 0; r < 8; ++r) {
      float4 h = *(const float4*)&hb[r][j4 * 4];
      aq[r] += dot4(h, a);
      ak[r] += dot4(h, b);
      av[r] += dot4(h, c);
    }
  }
#pragma unroll
  for (int r = 0; r < 8; ++r) {
    qg[(rows0 + r) * ND + t] = aq[r];
    kg[(rows0 + r) * ND + t] = ak[r];
    vg[(rows0 + r) * ND + t] = av[r];
  }
}

// ---------- Kernel C: attention, no-max softmax, key-split 4x across waves ----------
__global__ __launch_bounds__(256) void k_attn(
    const float* __restrict__ qg, const float* __restrict__ kg,
    const float* __restrict__ vg, const int* __restrict__ length,
    float* __restrict__ att) {
  __shared__ __align__(16) float smem[5376];  // Kt[2048] Vt[2048] / partial[4][64][21]
  float* Kt = smem;
  float* Vt = smem + 2048;
  int blk = blockIdx.x;
  int bb = blk >> 7;
  int hh = (blk >> 4) & 7;
  int qc = blk & 15;
  int t = threadIdx.x;
  int ql = t & 63;
  int ks = t >> 6;
  int qi = qc * 64 + ql;
  int len = length[bb];
  const float* qrow = qg + (size_t)(bb * NN + qi) * ND + hh * DH;
  float4 q0 = ((const float4*)qrow)[0];
  float4 q1 = ((const float4*)qrow)[1];
  float4 q2 = ((const float4*)qrow)[2];
  float4 q3 = ((const float4*)qrow)[3];
  float4 o0 = {0, 0, 0, 0}, o1 = {0, 0, 0, 0}, o2 = {0, 0, 0, 0},
         o3 = {0, 0, 0, 0};
  float l = 0.f;
  for (int t0 = 0; t0 < len; t0 += 128) {
    const float* kb = kg + (size_t)(bb * NN + t0) * ND + hh * DH;
    const float* vb = vg + (size_t)(bb * NN + t0) * ND + hh * DH;
#pragma unroll
    for (int f = t; f < 512; f += 256) {
      int j = f >> 2, c = f & 3;
      ((float4*)Kt)[f] = ((const float4*)(kb + j * ND))[c];
      ((float4*)Vt)[f] = ((const float4*)(vb + j * ND))[c];
    }
    __syncthreads();
    int jbase = ks * 32;
#pragma unroll 4
    for (int jj = 0; jj < 32; ++jj) {
      int j = jbase + jj;
      const float4* kr = ((const float4*)Kt) + j * 4;
      float s = dot4(q0, kr[0]) + dot4(q1, kr[1]) + dot4(q2, kr[2]) +
                dot4(q3, kr[3]);
      float p = ((t0 + j) < len) ? __expf(s * 0.25f) : 0.0f;
      l += p;
      const float4* vr = ((const float4*)Vt) + j * 4;
      float4 va = vr[0], vb4 = vr[1], vc4 = vr[2], vd4 = vr[3];
      o0.x += p * va.x;  o0.y += p * va.y;  o0.z += p * va.z;  o0.w += p * va.w;
      o1.x += p * vb4.x; o1.y += p * vb4.y; o1.z += p * vb4.z; o1.w += p * vb4.w;
      o2.x += p * vc4.x; o2.y += p * vc4.y; o2.z += p * vc4.z; o2.w += p * vc4.w;
      o3.x += p * vd4.x; o3.y += p * vd4.y; o3.z += p * vd4.z; o3.w += p * vd4.w;
    }
    __syncthreads();
  }
  // write partials and merge the 4 key-split groups
  float* pr = smem + (ks * 64 + ql) * 21;
  pr[0] = o0.x;  pr[1] = o0.y;  pr[2] = o0.z;  pr[3] = o0.w;
  pr[4] = o1.x;  pr[5] = o1.y;  pr[6] = o1.z;  pr[7] = o1.w;
  pr[8] = o2.x;  pr[9] = o2.y;  pr[10] = o2.z; pr[11] = o2.w;
  pr[12] = o3.x; pr[13] = o3.y; pr[14] = o3.z; pr[15] = o3.w;
  pr[16] = l;
  __syncthreads();
  int row = t >> 2, comp = t & 3;
  const float* p0 = smem + row * 21;
  const float* p1 = smem + (64 + row) * 21;
  const float* p2 = smem + (128 + row) * 21;
  const float* p3 = smem + (192 + row) * 21;
  float lsum = p0[16] + p1[16] + p2[16] + p3[16];
  float inv = 1.0f / lsum;
  int c0 = comp * 4;
  float4 val;
  val.x = (p0[c0] + p1[c0] + p2[c0] + p3[c0]) * inv;
  val.y = (p0[c0 + 1] + p1[c0 + 1] + p2[c0 + 1] + p3[c0 + 1]) * inv;
  val.z = (p0[c0 + 2] + p1[c0 + 2] + p2[c0 + 2] + p3[c0 + 2]) * inv;
  val.w = (p0[c0 + 3] + p1[c0 + 3] + p2[c0 + 3] + p3[c0 + 3]) * inv;
  float* orow = att + (size_t)(bb * NN + qc * 64 + row) * ND + hh * DH + c0;
  *(float4*)orow = val;
}

// ---------- Kernel B: out-proj + residual + LN2 + FFN (8 rows/block) ----------
__global__ __launch_bounds__(128) void kB(
    const float* __restrict__ att, const float* __restrict__ oW,
    const float* __restrict__ ob, const float* __restrict__ g2s,
    const float* __restrict__ g2b, const float* __restrict__ W1,
    const float* __restrict__ fb1, const float* __restrict__ W2,
    const float* __restrict__ fb2, float* __restrict__ eig) {
  __shared__ __align__(16) float ab[8][128];
  __shared__ __align__(16) float hb[8][128];
  __shared__ float scrA[8][2], scrB[8][2];
  int t = threadIdx.x;
  int rows0 = blockIdx.x * 8;
  // stage 8 att rows (contiguous 1024 floats)
  const float4* asrc = (const float4*)(att + (size_t)rows0 * ND);
  float4* adst = (float4*)ab;
  adst[t] = asrc[t];
  adst[t + 128] = asrc[t + 128];
  __syncthreads();
  // out-projection
  float acc[8];
  float obv = ob[t];
#pragma unroll
  for (int r = 0; r < 8; ++r) acc[r] = obv;
  const float4* wo = (const float4*)(oW + t * 128);
#pragma unroll 4
  for (int j4 = 0; j4 < 32; ++j4) {
    float4 w = wo[j4];
#pragma unroll
    for (int r = 0; r < 8; ++r)
      acc[r] += dot4(*(const float4*)&ab[r][j4 * 4], w);
  }
  // residual
  float x[8];
#pragma unroll
  for (int r = 0; r < 8; ++r) x[r] = eig[(rows0 + r) * ND + t] + acc[r];
  // LN2
  float ms[8];
  row8_reduce(x, ms, scrA, t);
  float xc[8], sq[8];
#pragma unroll
  for (int r = 0; r < 8; ++r) {
    xc[r] = x[r] - ms[r] * (1.0f / 128.0f);
    sq[r] = xc[r] * xc[r];
  }
  float vs[8];
  row8_reduce(sq, vs, scrB, t);
  float s2 = g2s[t], b2v = g2b[t];
#pragma unroll
  for (int r = 0; r < 8; ++r)
    hb[r][t] = xc[r] * rsqrtf(vs[r] * (1.0f / 128.0f) + 1e-5f) * s2 + b2v;
  __syncthreads();
  // FFN1 + exact gelu
  float g[8];
  float b1v = fb1[t];
#pragma unroll
  for (int r = 0; r < 8; ++r) g[r] = b1v;
  const float4* w1 = (const float4*)(W1 + t * 128);
#pragma unroll 4
  for (int j4 = 0; j4 < 32; ++j4) {
    float4 w = w1[j4];
#pragma unroll
    for (int r = 0; r < 8; ++r)
      g[r] += dot4(*(const float4*)&hb[r][j4 * 4], w);
  }
  __syncthreads();  // done reading ab in out-proj; safe to overwrite
#pragma unroll
  for (int r = 0; r < 8; ++r)
    ab[r][t] = 0.5f * g[r] * (1.0f + erff(g[r] * 0.7071067811865475f));
  __syncthreads();
  // FFN2 + residual
  float acc2[8];
  float b2f = fb2[t];
#pragma unroll
  for (int r = 0; r < 8; ++r) acc2[r] = b2f;
  const float4* w2 = (const float4*)(W2 + t * 128);
#pragma unroll 4
  for (int j4 = 0; j4 < 32; ++j4) {
    float4 w = w2[j4];
#pragma unroll
    for (int r = 0; r < 8; ++r)
      acc2[r] += dot4(*(const float4*)&ab[r][j4 * 4], w);
  }
#pragma unroll
  for (int r = 0; r < 8; ++r) eig[(rows0 + r) * ND + t] = x[r] + acc2[r];
}

// ---------- Kernel D: masked row-sum (pooling is linear in eig) ----------
__global__ __launch_bounds__(128) void kD(const float* __restrict__ eig,
                                          const int* __restrict__ length,
                                          float* __restrict__ rsum) {
  int b = blockIdx.x >> 4, c = blockIdx.x & 15, t = threadIdx.x;
  int len = length[b];
  int n0 = c * 64;
  float acc = 0.f;
  for (int i = 0; i < 64; ++i) {
    int n = n0 + i;
    if (n >= len) break;
    acc += eig[((size_t)b * NN + n) * ND + t];
  }
  rsum[(b * 16 + c) * ND + t] = acc;
}

// ---------- Kernel E: finish pooling + sigmoid + normalize coefficients ----------
__global__ __launch_bounds__(128) void kE(
    const float* __restrict__ rsum, const int* __restrict__ length,
    const float* __restrict__ dsW, const float* __restrict__ dsB,
    const float* __restrict__ dwW, const float* __restrict__ dwB,
    const float* __restrict__ dlW, const float* __restrict__ dlB,
    float* __restrict__ coe) {
  int b = blockIdx.x, t = threadIdx.x;
  __shared__ float s[128];
  __shared__ float pg[20];
  __shared__ float nrm[2];
  float a = 0.f;
#pragma unroll
  for (int c = 0; c < 16; ++c) a += rsum[(b * 16 + c) * ND + t];
  s[t] = a;
  __syncthreads();
  if (t < 20) {
    const float* W = t < 8 ? dsW + t * 128
                           : (t < 16 ? dwW + (t - 8) * 128 : dlW + (t - 16) * 128);
    float bias = t < 8 ? dsB[t] : (t < 16 ? dwB[t - 8] : dlB[t - 16]);
    float d = 0.f;
    for (int j = 0; j < 128; ++j) d += s[j] * W[j];
    float lf = (float)length[b];
    float pooled = (d + lf * bias) / (lf + 1e-8f);
    pg[t] = 1.f / (1.f + expf(-pooled));
  }
  __syncthreads();
  if (t == 0) {
    float a1 = 0.f, a2 = 0.f;
    for (int i = 0; i < 8; ++i) a1 += pg[i];
    for (int i = 8; i < 16; ++i) a2 += pg[i];
    nrm[0] = a1 + 1e-8f;
    nrm[1] = a2 + 1e-8f;
  }
  __syncthreads();
  if (t < 8) coe[b * 20 + t] = pg[t] / nrm[0];
  else if (t < 16) coe[b * 20 + t] = pg[t] / nrm[1];
  else if (t < 20) coe[b * 20 + t] = pg[t] * 2.0f;
}

// ---------- Kernel F: Chebyshev wave synthesis + tight frame ----------
__global__ __launch_bounds__(256) void k_wave(const float* __restrict__ eva,
                                              const float* __restrict__ coe,
                                              float* __restrict__ out) {
  int bn = blockIdx.x * 256 + threadIdx.x;
  int b = bn >> 10;
  float e = eva[bn];
  const float* cb = coe + b * 20;
  float y = e - 1.0f;
  float te = 1.0f, to = y;
  float cs = cb[0] * 0.5f * (1.0f - to);
#pragma unroll
  for (int i = 1; i < 8; ++i) {
    te = 2.f * y * to - te;
    to = 2.f * y * te - to;
    cs += cb[i] * 0.5f * (1.0f - to);
  }
  float cw[4];
#pragma unroll
  for (int j = 0; j < 4; ++j) {
    float fs = e * cb[16 + j];
    fs = (fs > 2.0f) ? 0.0f : fs;
    float yw = fs - 1.0f;
    float te2 = 1.0f, to2 = yw;
    float acc = 0.0f;  // cb[8]*0.5*(1-T0), T0=1 -> 0
#pragma unroll
    for (int i = 1; i < 8; ++i) {
      te2 = 2.f * yw * to2 - te2;
      to2 = 2.f * yw * te2 - to2;
      acc += cb[8 + i] * 0.5f * (1.0f - te2);
    }
    cw[j] = acc;
  }
  float nrm = cs * cs + cw[0] * cw[0] + cw[1] * cw[1] + cw[2] * cw[2] +
              cw[3] * cw[3];
  float inv = 1.0f / (sqrtf(nrm) + 1e-8f);
  float* o = out + bn * 5;
  o[0] = cs * inv;
  o[1] = cw[0] * inv;
  o[2] = cw[1] * inv;
  o[3] = cw[2] * inv;
  o[4] = cw[3] * inv;
}

extern "C" void kernel_launch(void* const* d_in, const int* in_sizes, int n_in,
                              void* d_out, int out_size, void* d_ws,
                              size_t ws_size, hipStream_t stream) {
  const float* eva = (const float*)d_in[1];
  const int* length = (const int*)d_in[2];
  const float* eig_w_W = (const float*)d_in[3];
  const float* eig_w_b = (const float*)d_in[4];
  const float* ln1_s = (const float*)d_in[5];
  const float* ln1_b = (const float*)d_in[6];
  const float* ln2_s = (const float*)d_in[7];
  const float* ln2_b = (const float*)d_in[8];
  const float* qkv_W = (const float*)d_in[9];
  const float* qkv_b = (const float*)d_in[10];
  const float* out_W = (const float*)d_in[11];
  const float* out_b = (const float*)d_in[12];
  const float* ffn_W1 = (const float*)d_in[13];
  const float* ffn_b1 = (const float*)d_in[14];
  const float* ffn_W2 = (const float*)d_in[15];
  const float* ffn_b2 = (const float*)d_in[16];
  const float* dec_sca_W = (const float*)d_in[17];
  const float* dec_sca_b = (const float*)d_in[18];
  const float* dec_wav_W = (const float*)d_in[19];
  const float* dec_wav_b = (const float*)d_in[20];
  const float* dec_scl_W = (const float*)d_in[21];
  const float* dec_scl_b = (const float*)d_in[22];

  float* ws = (float*)d_ws;
  const int SZ = NB * NN * ND;
  float* eig = ws;
  float* q = ws + (size_t)SZ;
  float* k = ws + (size_t)2 * SZ;
  float* v = ws + (size_t)3 * SZ;
  float* att = ws + (size_t)4 * SZ;
  float* rsum = ws + (size_t)5 * SZ;       // [B*16*128]
  float* coe = rsum + NB * 16 * ND;        // [B*20]

  kA<<<NB * NN / 8, 128, 0, stream>>>(eva, eig_w_W, eig_w_b, ln1_s, ln1_b,
                                      qkv_W, qkv_b, eig, q, k, v);
  k_attn<<<NB * NH * 16, 256, 0, stream>>>(q, k, v, length, att);
  kB<<<NB * NN / 8, 128, 0, stream>>>(att, out_W, out_b, ln2_s, ln2_b, ffn_W1,
                                      ffn_b1, ffn_W2, ffn_b2, eig);
  kD<<<NB * 16, 128, 0, stream>>>(eig, length, rsum);
  kE<<<NB, 128, 0, stream>>>(rsum, length, dec_sca_W, dec_sca_b, dec_wav_W,
                             dec_wav_b, dec_scl_W, dec_scl_b, coe);
  k_wave<<<(NB * NN) / 256, 256, 0, stream>>>(eva, coe, (float*)d_out);
}

// Round 5
// 198.121 us; speedup vs baseline: 6.3045x; 1.6935x over previous
//
#include <hip/hip_runtime.h>
#include <math.h>

#define NB 16
#define NN 1024
#define ND 128
#define NH 8
#define DH 16

typedef float f32x4 __attribute__((ext_vector_type(4)));
typedef short s16x4 __attribute__((ext_vector_type(4)));

static __device__ __forceinline__ float dot4(float4 a, float4 b) {
  return a.x * b.x + a.y * b.y + a.z * b.z + a.w * b.w;
}

static __device__ __forceinline__ ushort f2bf(float x) {
  unsigned u = __float_as_uint(x);
  u = (u + 0x7FFFu + ((u >> 16) & 1u)) >> 16;
  return (ushort)u;
}

// D = A(16x16 bf16) * B(16x16 bf16) + C, 16x16x16.
// Use the builtin so the compiler inserts the mandatory MFMA<->VALU hazard
// nops (raw inline asm hides the MFMA from the hazard recognizer -> NaN).
static __device__ __forceinline__ f32x4 mfma16(s16x4 a, s16x4 b, f32x4 c) {
#if __has_builtin(__builtin_amdgcn_mfma_f32_16x16x16bf16_1k)
  return __builtin_amdgcn_mfma_f32_16x16x16bf16_1k(a, b, c, 0, 0, 0);
#else
  asm volatile(
      "s_nop 1\n\t"
      "v_mfma_f32_16x16x16_bf16 %0, %1, %2, %0\n\t"
      "s_nop 7\n\t"
      "s_nop 7"
      : "+v"(c)
      : "v"(a), "v"(b));
  return c;
#endif
}

// reduce 8 per-thread values across a 128-thread block (2 waves)
static __device__ __forceinline__ void row8_reduce(const float v[8], float out[8],
                                                   float (*scr)[2], int t) {
  int lane = t & 63, w = t >> 6;
#pragma unroll
  for (int r = 0; r < 8; ++r) {
    float x = v[r];
#pragma unroll
    for (int off = 32; off > 0; off >>= 1) x += __shfl_down(x, off, 64);
    if (lane == 0) scr[r][w] = x;
  }
  __syncthreads();
#pragma unroll
  for (int r = 0; r < 8; ++r) out[r] = scr[r][0] + scr[r][1];
}

// ---------- Kernel A: sine-encoding + eig linear + LN1 + QKV (8 rows/block) ----------
// q/k/v written as bf16 in [b, h, n, 16] layout for the MFMA attention.
__global__ __launch_bounds__(128) void kA(
    const float* __restrict__ eva, const float* __restrict__ eW,
    const float* __restrict__ eb, const float* __restrict__ g1s,
    const float* __restrict__ g1b, const float* __restrict__ qW,
    const float* __restrict__ qb, float* __restrict__ eig,
    ushort* __restrict__ qg, ushort* __restrict__ kg, ushort* __restrict__ vg) {
  __shared__ __align__(16) float ee[8][132];
  __shared__ __align__(16) float hb[8][128];
  __shared__ float scrA[8][2], scrB[8][2];
  int t = threadIdx.x;
  int rows0 = blockIdx.x * 8;
  int d64 = t & 63;
  float div = expf((float)(2 * d64) * (-9.210340371976184f / 128.0f));
#pragma unroll
  for (int r = 0; r < 8; ++r) {
    float e = eva[rows0 + r];
    if (t == 0) ee[r][0] = e;
    float pe = e * 100.0f * div;
    if (t < 64) ee[r][1 + d64] = sinf(pe);
    else ee[r][65 + d64] = cosf(pe);
  }
  __syncthreads();
  float acc[8];
#pragma unroll
  for (int r = 0; r < 8; ++r) acc[r] = eb[t];
  const float* wr = eW + t * 129;
#pragma unroll 4
  for (int j4 = 0; j4 < 32; ++j4) {
    float w0 = wr[j4 * 4], w1 = wr[j4 * 4 + 1], w2 = wr[j4 * 4 + 2],
          w3 = wr[j4 * 4 + 3];
#pragma unroll
    for (int r = 0; r < 8; ++r) {
      float4 ev = *(const float4*)&ee[r][j4 * 4];
      acc[r] += ev.x * w0 + ev.y * w1 + ev.z * w2 + ev.w * w3;
    }
  }
  {
    float w = wr[128];
#pragma unroll
    for (int r = 0; r < 8; ++r) acc[r] += ee[r][128] * w;
  }
#pragma unroll
  for (int r = 0; r < 8; ++r) eig[(rows0 + r) * ND + t] = acc[r];
  // LN1
  float ms[8];
  row8_reduce(acc, ms, scrA, t);
  float xc[8], sq[8];
#pragma unroll
  for (int r = 0; r < 8; ++r) {
    xc[r] = acc[r] - ms[r] * (1.0f / 128.0f);
    sq[r] = xc[r] * xc[r];
  }
  float vs[8];
  row8_reduce(sq, vs, scrB, t);
  float s1 = g1s[t], b1v = g1b[t];
#pragma unroll
  for (int r = 0; r < 8; ++r)
    hb[r][t] = xc[r] * rsqrtf(vs[r] * (1.0f / 128.0f) + 1e-5f) * s1 + b1v;
  __syncthreads();
  // QKV
  float aq[8], ak[8], av[8];
  float bq = qb[t], bk = qb[128 + t], bv = qb[256 + t];
#pragma unroll
  for (int r = 0; r < 8; ++r) { aq[r] = bq; ak[r] = bk; av[r] = bv; }
  const float4* wq = (const float4*)(qW + t * 128);
  const float4* wk = (const float4*)(qW + (128 + t) * 128);
  const float4* wv = (const float4*)(qW + (256 + t) * 128);
#pragma unroll 4
  for (int j4 = 0; j4 < 32; ++j4) {
    float4 a = wq[j4], b = wk[j4], c = wv[j4];
#pragma unroll
    for (int r = 0; r < 8; ++r) {
      float4 h = *(const float4*)&hb[r][j4 * 4];
      aq[r] += dot4(h, a);
      ak[r] += dot4(h, b);
      av[r] += dot4(h, c);
    }
  }
  int bidx = rows0 >> 10;
  int nn0 = rows0 & 1023;
  int h = t >> 4, d = t & 15;
  size_t base = ((size_t)(bidx * NH + h) * NN + nn0) * DH + d;
#pragma unroll
  for (int r = 0; r < 8; ++r) {
    qg[base + r * DH] = f2bf(aq[r]);
    kg[base + r * DH] = f2bf(ak[r]);
    vg[base + r * DH] = f2bf(av[r]);
  }
}

// ---------- Kernel C: MFMA attention ----------
// block = 512 thr = 8 waves; each wave owns 16 queries; 128 queries/block.
// per 16-key tile: S^T = mfma(K, Q^T)  ->  p = exp(s/4) masked  ->
// O^T += mfma(V^T, P^T)  (P^T comes straight from S^T's C layout).
__global__ __launch_bounds__(512) void k_attn(
    const ushort* __restrict__ qg, const ushort* __restrict__ kg,
    const ushort* __restrict__ vg, const int* __restrict__ length,
    float* __restrict__ att) {
  __shared__ ushort Ksh[128][20];   // padded rows: conflict-free b64 reads
  __shared__ ushort VTsh[16][136];  // V transposed [dh][key], padded
  int bid = blockIdx.x;
  int bh = bid >> 3, qc = bid & 7;
  int b = bh >> 3, h = bh & 7;
  int t = threadIdx.x;
  int w = t >> 6, l = t & 63;
  int g = l >> 4, c = l & 15;
  int len = length[b];
  int qrow = qc * 128 + w * 16 + c;
  // Q B-frag: Q[q=c][dh=4g..4g+3]
  s16x4 qf = *(const s16x4*)(qg + ((size_t)bh * NN + qrow) * DH + g * 4);
  f32x4 oacc = {0.f, 0.f, 0.f, 0.f};
  float lsum = 0.f;
  int sr = t >> 2, sc = t & 3;  // staging: row, quarter
  for (int t0 = 0; t0 < len; t0 += 128) {
    uint2 kv = {0u, 0u}, vv = {0u, 0u};
    if (t0 + sr < len) {
      size_t gofs = ((size_t)bh * NN + t0 + sr) * DH + sc * 4;
      kv = *(const uint2*)(kg + gofs);
      vv = *(const uint2*)(vg + gofs);
    }
    *(uint2*)&Ksh[sr][sc * 4] = kv;
    VTsh[sc * 4 + 0][sr] = (ushort)(vv.x & 0xffffu);
    VTsh[sc * 4 + 1][sr] = (ushort)(vv.x >> 16);
    VTsh[sc * 4 + 2][sr] = (ushort)(vv.y & 0xffffu);
    VTsh[sc * 4 + 3][sr] = (ushort)(vv.y >> 16);
    __syncthreads();
#pragma unroll
    for (int kt = 0; kt < 8; ++kt) {
      int kbase = t0 + kt * 16;
      if (kbase >= len) break;
      // A-frag: K[key=c][dh=4g..]; B-frag: qf
      s16x4 kf = *(const s16x4*)&Ksh[kt * 16 + c][g * 4];
      f32x4 st = {0.f, 0.f, 0.f, 0.f};
      st = mfma16(kf, qf, st);
      // lane's scores: query c, keys kbase + 4g + j
      int kj = kbase + g * 4;
      float p0 = (kj + 0 < len) ? __expf(st[0] * 0.25f) : 0.f;
      float p1 = (kj + 1 < len) ? __expf(st[1] * 0.25f) : 0.f;
      float p2 = (kj + 2 < len) ? __expf(st[2] * 0.25f) : 0.f;
      float p3 = (kj + 3 < len) ? __expf(st[3] * 0.25f) : 0.f;
      lsum += (p0 + p1) + (p2 + p3);
      s16x4 pf = {(short)f2bf(p0), (short)f2bf(p1), (short)f2bf(p2),
                  (short)f2bf(p3)};
      // A-frag: V^T[d=c][key=kt*16+4g..]
      s16x4 vf = *(const s16x4*)&VTsh[c][kt * 16 + g * 4];
      oacc = mfma16(vf, pf, oacc);
    }
    __syncthreads();
  }
  lsum += __shfl_xor(lsum, 16, 64);
  lsum += __shfl_xor(lsum, 32, 64);
  float inv = 1.0f / lsum;
  // O^T: row = d = 4g+j, col = q = c -> float4 store
  float4 o = make_float4(oacc[0] * inv, oacc[1] * inv, oacc[2] * inv,
                         oacc[3] * inv);
  *(float4*)(att + ((size_t)b * NN + qrow) * ND + h * DH + g * 4) = o;
}

// ---------- Kernel B: out-proj + residual + LN2 + FFN (8 rows/block) ----------
__global__ __launch_bounds__(128) void kB(
    const float* __restrict__ att, const float* __restrict__ oW,
    const float* __restrict__ ob, const float* __restrict__ g2s,
    const float* __restrict__ g2b, const float* __restrict__ W1,
    const float* __restrict__ fb1, const float* __restrict__ W2,
    const float* __restrict__ fb2, float* __restrict__ eig) {
  __shared__ __align__(16) float ab[8][128];
  __shared__ __align__(16) float hb[8][128];
  __shared__ float scrA[8][2], scrB[8][2];
  int t = threadIdx.x;
  int rows0 = blockIdx.x * 8;
  const float4* asrc = (const float4*)(att + (size_t)rows0 * ND);
  float4* adst = (float4*)ab;
  adst[t] = asrc[t];
  adst[t + 128] = asrc[t + 128];
  __syncthreads();
  float acc[8];
  float obv = ob[t];
#pragma unroll
  for (int r = 0; r < 8; ++r) acc[r] = obv;
  const float4* wo = (const float4*)(oW + t * 128);
#pragma unroll 4
  for (int j4 = 0; j4 < 32; ++j4) {
    float4 w = wo[j4];
#pragma unroll
    for (int r = 0; r < 8; ++r)
      acc[r] += dot4(*(const float4*)&ab[r][j4 * 4], w);
  }
  float x[8];
#pragma unroll
  for (int r = 0; r < 8; ++r) x[r] = eig[(rows0 + r) * ND + t] + acc[r];
  float ms[8];
  row8_reduce(x, ms, scrA, t);
  float xc[8], sq[8];
#pragma unroll
  for (int r = 0; r < 8; ++r) {
    xc[r] = x[r] - ms[r] * (1.0f / 128.0f);
    sq[r] = xc[r] * xc[r];
  }
  float vs[8];
  row8_reduce(sq, vs, scrB, t);
  float s2 = g2s[t], b2v = g2b[t];
#pragma unroll
  for (int r = 0; r < 8; ++r)
    hb[r][t] = xc[r] * rsqrtf(vs[r] * (1.0f / 128.0f) + 1e-5f) * s2 + b2v;
  __syncthreads();
  float g[8];
  float b1v = fb1[t];
#pragma unroll
  for (int r = 0; r < 8; ++r) g[r] = b1v;
  const float4* w1 = (const float4*)(W1 + t * 128);
#pragma unroll 4
  for (int j4 = 0; j4 < 32; ++j4) {
    float4 w = w1[j4];
#pragma unroll
    for (int r = 0; r < 8; ++r)
      g[r] += dot4(*(const float4*)&hb[r][j4 * 4], w);
  }
  __syncthreads();
#pragma unroll
  for (int r = 0; r < 8; ++r)
    ab[r][t] = 0.5f * g[r] * (1.0f + erff(g[r] * 0.7071067811865475f));
  __syncthreads();
  float acc2[8];
  float b2f = fb2[t];
#pragma unroll
  for (int r = 0; r < 8; ++r) acc2[r] = b2f;
  const float4* w2 = (const float4*)(W2 + t * 128);
#pragma unroll 4
  for (int j4 = 0; j4 < 32; ++j4) {
    float4 w = w2[j4];
#pragma unroll
    for (int r = 0; r < 8; ++r)
      acc2[r] += dot4(*(const float4*)&ab[r][j4 * 4], w);
  }
#pragma unroll
  for (int r = 0; r < 8; ++r) eig[(rows0 + r) * ND + t] = x[r] + acc2[r];
}

// ---------- Kernel D: masked row-sum (pooling is linear in eig) ----------
__global__ __launch_bounds__(128) void kD(const float* __restrict__ eig,
                                          const int* __restrict__ length,
                                          float* __restrict__ rsum) {
  int b = blockIdx.x >> 4, c = blockIdx.x & 15, t = threadIdx.x;
  int len = length[b];
  int n0 = c * 64;
  float acc = 0.f;
  for (int i = 0; i < 64; ++i) {
    int n = n0 + i;
    if (n >= len) break;
    acc += eig[((size_t)b * NN + n) * ND + t];
  }
  rsum[(b * 16 + c) * ND + t] = acc;
}

// ---------- Kernel E: finish pooling + sigmoid + normalize coefficients ----------
__global__ __launch_bounds__(128) void kE(
    const float* __restrict__ rsum, const int* __restrict__ length,
    const float* __restrict__ dsW, const float* __restrict__ dsB,
    const float* __restrict__ dwW, const float* __restrict__ dwB,
    const float* __restrict__ dlW, const float* __restrict__ dlB,
    float* __restrict__ coe) {
  int b = blockIdx.x, t = threadIdx.x;
  __shared__ float s[128];
  __shared__ float pg[20];
  __shared__ float nrm[2];
  float a = 0.f;
#pragma unroll
  for (int c = 0; c < 16; ++c) a += rsum[(b * 16 + c) * ND + t];
  s[t] = a;
  __syncthreads();
  if (t < 20) {
    const float* W = t < 8 ? dsW + t * 128
                           : (t < 16 ? dwW + (t - 8) * 128 : dlW + (t - 16) * 128);
    float bias = t < 8 ? dsB[t] : (t < 16 ? dwB[t - 8] : dlB[t - 16]);
    float d = 0.f;
    for (int j = 0; j < 128; ++j) d += s[j] * W[j];
    float lf = (float)length[b];
    float pooled = (d + lf * bias) / (lf + 1e-8f);
    pg[t] = 1.f / (1.f + expf(-pooled));
  }
  __syncthreads();
  if (t == 0) {
    float a1 = 0.f, a2 = 0.f;
    for (int i = 0; i < 8; ++i) a1 += pg[i];
    for (int i = 8; i < 16; ++i) a2 += pg[i];
    nrm[0] = a1 + 1e-8f;
    nrm[1] = a2 + 1e-8f;
  }
  __syncthreads();
  if (t < 8) coe[b * 20 + t] = pg[t] / nrm[0];
  else if (t < 16) coe[b * 20 + t] = pg[t] / nrm[1];
  else if (t < 20) coe[b * 20 + t] = pg[t] * 2.0f;
}

// ---------- Kernel F: Chebyshev wave synthesis + tight frame ----------
__global__ __launch_bounds__(256) void k_wave(const float* __restrict__ eva,
                                              const float* __restrict__ coe,
                                              float* __restrict__ out) {
  int bn = blockIdx.x * 256 + threadIdx.x;
  int b = bn >> 10;
  float e = eva[bn];
  const float* cb = coe + b * 20;
  float y = e - 1.0f;
  float te = 1.0f, to = y;
  float cs = cb[0] * 0.5f * (1.0f - to);
#pragma unroll
  for (int i = 1; i < 8; ++i) {
    te = 2.f * y * to - te;
    to = 2.f * y * te - to;
    cs += cb[i] * 0.5f * (1.0f - to);
  }
  float cw[4];
#pragma unroll
  for (int j = 0; j < 4; ++j) {
    float fs = e * cb[16 + j];
    fs = (fs > 2.0f) ? 0.0f : fs;
    float yw = fs - 1.0f;
    float te2 = 1.0f, to2 = yw;
    float acc = 0.0f;
#pragma unroll
    for (int i = 1; i < 8; ++i) {
      te2 = 2.f * yw * to2 - te2;
      to2 = 2.f * yw * te2 - to2;
      acc += cb[8 + i] * 0.5f * (1.0f - te2);
    }
    cw[j] = acc;
  }
  float nrm = cs * cs + cw[0] * cw[0] + cw[1] * cw[1] + cw[2] * cw[2] +
              cw[3] * cw[3];
  float inv = 1.0f / (sqrtf(nrm) + 1e-8f);
  float* o = out + bn * 5;
  o[0] = cs * inv;
  o[1] = cw[0] * inv;
  o[2] = cw[1] * inv;
  o[3] = cw[2] * inv;
  o[4] = cw[3] * inv;
}

extern "C" void kernel_launch(void* const* d_in, const int* in_sizes, int n_in,
                              void* d_out, int out_size, void* d_ws,
                              size_t ws_size, hipStream_t stream) {
  const float* eva = (const float*)d_in[1];
  const int* length = (const int*)d_in[2];
  const float* eig_w_W = (const float*)d_in[3];
  const float* eig_w_b = (const float*)d_in[4];
  const float* ln1_s = (const float*)d_in[5];
  const float* ln1_b = (const float*)d_in[6];
  const float* ln2_s = (const float*)d_in[7];
  const float* ln2_b = (const float*)d_in[8];
  const float* qkv_W = (const float*)d_in[9];
  const float* qkv_b = (const float*)d_in[10];
  const float* out_W = (const float*)d_in[11];
  const float* out_b = (const float*)d_in[12];
  const float* ffn_W1 = (const float*)d_in[13];
  const float* ffn_b1 = (const float*)d_in[14];
  const float* ffn_W2 = (const float*)d_in[15];
  const float* ffn_b2 = (const float*)d_in[16];
  const float* dec_sca_W = (const float*)d_in[17];
  const float* dec_sca_b = (const float*)d_in[18];
  const float* dec_wav_W = (const float*)d_in[19];
  const float* dec_wav_b = (const float*)d_in[20];
  const float* dec_scl_W = (const float*)d_in[21];
  const float* dec_scl_b = (const float*)d_in[22];

  float* ws = (float*)d_ws;
  const size_t SZ = (size_t)NB * NN * ND;          // 2097152 floats
  const size_t QSZ = (size_t)NB * NH * NN * DH;    // 2097152 bf16 elems
  float* eig = ws;
  float* att = ws + SZ;
  ushort* qg = (ushort*)(ws + 2 * SZ);
  ushort* kg = qg + QSZ;
  ushort* vg = kg + QSZ;
  float* rsum = (float*)(vg + QSZ);  // [B*16*128]
  float* coe = rsum + NB * 16 * ND;  // [B*20]

  kA<<<NB * NN / 8, 128, 0, stream>>>(eva, eig_w_W, eig_w_b, ln1_s, ln1_b,
                                      qkv_W, qkv_b, eig, qg, kg, vg);
  k_attn<<<NB * NH * 8, 512, 0, stream>>>(qg, kg, vg, length, att);
  kB<<<NB * NN / 8, 128, 0, stream>>>(att, out_W, out_b, ln2_s, ln2_b, ffn_W1,
                                      ffn_b1, ffn_W2, ffn_b2, eig);
  kD<<<NB * 16, 128, 0, stream>>>(eig, length, rsum);
  kE<<<NB, 128, 0, stream>>>(rsum, length, dec_sca_W, dec_sca_b, dec_wav_W,
                             dec_wav_b, dec_scl_W, dec_scl_b, coe);
  k_wave<<<(NB * NN) / 256, 256, 0, stream>>>(eva, coe, (float*)d_out);
}

// Round 6
// 127.944 us; speedup vs baseline: 9.7625x; 1.5485x over previous
//
#include <hip/hip_runtime.h>
#include <math.h>

#define NB 16
#define NN 1024
#define ND 128
#define NH 8
#define DH 16

typedef float f32x4 __attribute__((ext_vector_type(4)));
typedef short s16x4 __attribute__((ext_vector_type(4)));

static __device__ __forceinline__ ushort f2bf(float x) {
  unsigned u = __float_as_uint(x);
  u = (u + 0x7FFFu + ((u >> 16) & 1u)) >> 16;
  return (ushort)u;
}

// D[a][b] = sum_k X[a][k]*Y[b][k] + C.  X/Y frag: lane l holds row (l&15),
// k = 4*(l>>4)..+3.  D: lane l holds rows 4*(l>>4)+j (j=0..3), col l&15.
// (convention hardware-verified by the passing R5 attention kernel)
static __device__ __forceinline__ f32x4 mfma16(s16x4 a, s16x4 b, f32x4 c) {
  return __builtin_amdgcn_mfma_f32_16x16x16bf16_1k(a, b, c, 0, 0, 0);
}

// ---------- Kernel W: one-time weight conversion to bf16 ----------
// layout in wbf: [0,18432) eW padded to [128][144]; [18432,67584) qkv [384][128];
// [67584,83968) out [128][128]; [83968,100352) ffn1; [100352,116736) ffn2
__global__ __launch_bounds__(256) void kW(
    const float* __restrict__ eW, const float* __restrict__ qkvW,
    const float* __restrict__ outW, const float* __restrict__ W1,
    const float* __restrict__ W2, ushort* __restrict__ wbf) {
  int i = blockIdx.x * 256 + threadIdx.x;
  if (i < 18432) {
    int r = i / 144, k = i - r * 144;
    wbf[i] = (k < 129) ? f2bf(eW[r * 129 + k]) : (ushort)0;
  } else if (i < 67584) {
    wbf[i] = f2bf(qkvW[i - 18432]);
  } else if (i < 83968) {
    wbf[i] = f2bf(outW[i - 67584]);
  } else if (i < 100352) {
    wbf[i] = f2bf(W1[i - 83968]);
  } else if (i < 116736) {
    wbf[i] = f2bf(W2[i - 100352]);
  }
}

// ---------- Kernel A: sine-enc + eig linear + LN1 + QKV, MFMA, 32 rows/block ----------
__global__ __launch_bounds__(256, 4) void kA(
    const float* __restrict__ eva, const ushort* __restrict__ eWbf,
    const float* __restrict__ eb, const float* __restrict__ g1s,
    const float* __restrict__ g1b, const ushort* __restrict__ qkvbf,
    const float* __restrict__ qb, float* __restrict__ eig,
    ushort* __restrict__ qg, ushort* __restrict__ kg,
    ushort* __restrict__ vg) {
  __shared__ __align__(16) ushort ee[32][148];   // stride 148: conflict-free frag reads
  __shared__ __align__(16) float eig_f[32][132];
  __shared__ __align__(16) ushort hbf[32][132];
  int t = threadIdx.x;
  int rows0 = blockIdx.x * 32;
  int w = t >> 6, l = t & 63, g = l >> 4, c = l & 15;

  // phase 1: ee = [eva, sin(pe), cos(pe)], bf16, cols 129..147 zeroed
  for (int i = t; i < 2048; i += 256) {
    int row = i >> 6, d = i & 63;
    float e = eva[rows0 + row];
    float div = expf((float)(2 * d) * (-9.210340371976184f / 128.0f));
    float pe = e * 100.0f * div;
    ee[row][1 + d] = f2bf(sinf(pe));
    ee[row][65 + d] = f2bf(cosf(pe));
    if (d == 0) ee[row][0] = f2bf(e);
  }
  for (int i = t; i < 32 * 19; i += 256) {
    int row = i / 19, cc = 129 + (i - row * 19);
    ee[row][cc] = 0;
  }
  __syncthreads();

  // phase 2: eig = ee @ eW^T + eb   (K = 144, 9 mfma steps; 4 tiles/wave)
  {
    int rt = w >> 1;
#pragma unroll
    for (int i = 0; i < 4; ++i) {
      int ct = (w & 1) * 4 + i;
      f32x4 st = {0.f, 0.f, 0.f, 0.f};
#pragma unroll
      for (int kk = 0; kk < 9; ++kk) {
        s16x4 xf = *(const s16x4*)&ee[rt * 16 + c][kk * 16 + g * 4];
        s16x4 yf = *(const s16x4*)&eWbf[(ct * 16 + c) * 144 + kk * 16 + g * 4];
        st = mfma16(xf, yf, st);
      }
      float bias = eb[ct * 16 + c];
#pragma unroll
      for (int j = 0; j < 4; ++j)
        eig_f[rt * 16 + g * 4 + j][ct * 16 + c] = st[j] + bias;
    }
  }
  __syncthreads();

  // write eig (f32, coalesced) for residual use in kB
#pragma unroll
  for (int p = 0; p < 4; ++p) {
    int idx = p * 256 + t;
    int row = idx >> 5, c4 = idx & 31;
    *(float4*)&eig[(size_t)(rows0 + row) * ND + c4 * 4] =
        *(const float4*)&eig_f[row][c4 * 4];
  }

  // LN1: row = t>>3, 8 lanes/row, stride-8 column interleave (conflict-free)
  {
    int row = t >> 3, s = t & 7;
    float vals[16];
    float sum = 0.f;
#pragma unroll
    for (int k = 0; k < 16; ++k) {
      vals[k] = eig_f[row][s + 8 * k];
      sum += vals[k];
    }
    sum += __shfl_xor(sum, 1, 8);
    sum += __shfl_xor(sum, 2, 8);
    sum += __shfl_xor(sum, 4, 8);
    float mean = sum * (1.0f / 128.0f);
    float sq = 0.f;
#pragma unroll
    for (int k = 0; k < 16; ++k) {
      float d = vals[k] - mean;
      sq += d * d;
    }
    sq += __shfl_xor(sq, 1, 8);
    sq += __shfl_xor(sq, 2, 8);
    sq += __shfl_xor(sq, 4, 8);
    float rstd = rsqrtf(sq * (1.0f / 128.0f) + 1e-5f);
#pragma unroll
    for (int k = 0; k < 16; ++k) {
      int col = s + 8 * k;
      hbf[row][col] = f2bf((vals[k] - mean) * rstd * g1s[col] + g1b[col]);
    }
  }
  __syncthreads();

  // phase 3: QKV = h @ qkvW^T + qb  (48 tiles, 12/wave), store bf16 [b,h,n,16]
  {
    int rt = w >> 1;
    int b = rows0 >> 10, nn0 = rows0 & 1023;
#pragma unroll
    for (int i = 0; i < 12; ++i) {
      int ct = (w & 1) * 12 + i;
      f32x4 st = {0.f, 0.f, 0.f, 0.f};
#pragma unroll
      for (int kk = 0; kk < 8; ++kk) {
        s16x4 xf = *(const s16x4*)&hbf[rt * 16 + c][kk * 16 + g * 4];
        s16x4 yf = *(const s16x4*)&qkvbf[(ct * 16 + c) * 128 + kk * 16 + g * 4];
        st = mfma16(xf, yf, st);
      }
      float bias = qb[ct * 16 + c];
      int which = ct >> 3, head = ct & 7;
      ushort* dst = which == 0 ? qg : (which == 1 ? kg : vg);
      size_t base =
          ((size_t)(b * NH + head) * NN + nn0 + rt * 16 + g * 4) * DH + c;
#pragma unroll
      for (int j = 0; j < 4; ++j) dst[base + j * DH] = f2bf(st[j] + bias);
    }
  }
}

// ---------- Kernel C: MFMA attention (R5, unchanged except bf16 output) ----------
__global__ __launch_bounds__(512) void k_attn(
    const ushort* __restrict__ qg, const ushort* __restrict__ kg,
    const ushort* __restrict__ vg, const int* __restrict__ length,
    ushort* __restrict__ att) {
  __shared__ ushort Ksh[128][20];
  __shared__ ushort VTsh[16][136];
  int bid = blockIdx.x;
  int bh = bid >> 3, qc = bid & 7;
  int b = bh >> 3, h = bh & 7;
  int t = threadIdx.x;
  int w = t >> 6, l = t & 63;
  int g = l >> 4, c = l & 15;
  int len = length[b];
  int qrow = qc * 128 + w * 16 + c;
  s16x4 qf = *(const s16x4*)(qg + ((size_t)bh * NN + qrow) * DH + g * 4);
  f32x4 oacc = {0.f, 0.f, 0.f, 0.f};
  float lsum = 0.f;
  int sr = t >> 2, sc = t & 3;
  for (int t0 = 0; t0 < len; t0 += 128) {
    uint2 kv = {0u, 0u}, vv = {0u, 0u};
    if (t0 + sr < len) {
      size_t gofs = ((size_t)bh * NN + t0 + sr) * DH + sc * 4;
      kv = *(const uint2*)(kg + gofs);
      vv = *(const uint2*)(vg + gofs);
    }
    *(uint2*)&Ksh[sr][sc * 4] = kv;
    VTsh[sc * 4 + 0][sr] = (ushort)(vv.x & 0xffffu);
    VTsh[sc * 4 + 1][sr] = (ushort)(vv.x >> 16);
    VTsh[sc * 4 + 2][sr] = (ushort)(vv.y & 0xffffu);
    VTsh[sc * 4 + 3][sr] = (ushort)(vv.y >> 16);
    __syncthreads();
#pragma unroll
    for (int kt = 0; kt < 8; ++kt) {
      int kbase = t0 + kt * 16;
      if (kbase >= len) break;
      s16x4 kf = *(const s16x4*)&Ksh[kt * 16 + c][g * 4];
      f32x4 st = {0.f, 0.f, 0.f, 0.f};
      st = mfma16(kf, qf, st);
      int kj = kbase + g * 4;
      float p0 = (kj + 0 < len) ? __expf(st[0] * 0.25f) : 0.f;
      float p1 = (kj + 1 < len) ? __expf(st[1] * 0.25f) : 0.f;
      float p2 = (kj + 2 < len) ? __expf(st[2] * 0.25f) : 0.f;
      float p3 = (kj + 3 < len) ? __expf(st[3] * 0.25f) : 0.f;
      lsum += (p0 + p1) + (p2 + p3);
      s16x4 pf = {(short)f2bf(p0), (short)f2bf(p1), (short)f2bf(p2),
                  (short)f2bf(p3)};
      s16x4 vf = *(const s16x4*)&VTsh[c][kt * 16 + g * 4];
      oacc = mfma16(vf, pf, oacc);
    }
    __syncthreads();
  }
  lsum += __shfl_xor(lsum, 16, 64);
  lsum += __shfl_xor(lsum, 32, 64);
  float inv = 1.0f / lsum;
  uint p01 = (uint)f2bf(oacc[0] * inv) | ((uint)f2bf(oacc[1] * inv) << 16);
  uint p23 = (uint)f2bf(oacc[2] * inv) | ((uint)f2bf(oacc[3] * inv) << 16);
  uint2 pk;
  pk.x = p01;
  pk.y = p23;
  *(uint2*)(att + ((size_t)b * NN + qrow) * ND + h * DH + g * 4) = pk;
}

// ---------- Kernel B: outproj + residual + LN2 + FFN, MFMA, 32 rows/block ----------
__global__ __launch_bounds__(256, 4) void kB(
    const ushort* __restrict__ attg, const ushort* __restrict__ outbf,
    const float* __restrict__ ob, const float* __restrict__ g2s,
    const float* __restrict__ g2b, const ushort* __restrict__ w1bf,
    const float* __restrict__ fb1, const ushort* __restrict__ w2bf,
    const float* __restrict__ fb2, float* __restrict__ eig) {
  __shared__ __align__(16) ushort attb[32][136];  // also reused as gelu buffer
  __shared__ __align__(16) float eig_f[32][132];
  __shared__ __align__(16) ushort hbf[32][132];
  int t = threadIdx.x;
  int rows0 = blockIdx.x * 32;
  int w = t >> 6, l = t & 63, g = l >> 4, c = l & 15;
  int rt = w >> 1;

  // stage att (bf16) and eig residual (f32), coalesced
#pragma unroll
  for (int p = 0; p < 2; ++p) {
    int idx = p * 256 + t;
    int row = idx >> 4, c8 = idx & 15;
    *(uint4*)&attb[row][c8 * 8] =
        *(const uint4*)&attg[(size_t)(rows0 + row) * ND + c8 * 8];
  }
#pragma unroll
  for (int p = 0; p < 4; ++p) {
    int idx = p * 256 + t;
    int row = idx >> 5, c4 = idx & 31;
    *(float4*)&eig_f[row][c4 * 4] =
        *(const float4*)&eig[(size_t)(rows0 + row) * ND + c4 * 4];
  }
  __syncthreads();

  // outproj + residual -> eig_f (x)
#pragma unroll
  for (int i = 0; i < 4; ++i) {
    int ct = (w & 1) * 4 + i;
    f32x4 st = {0.f, 0.f, 0.f, 0.f};
#pragma unroll
    for (int kk = 0; kk < 8; ++kk) {
      s16x4 xf = *(const s16x4*)&attb[rt * 16 + c][kk * 16 + g * 4];
      s16x4 yf = *(const s16x4*)&outbf[(ct * 16 + c) * 128 + kk * 16 + g * 4];
      st = mfma16(xf, yf, st);
    }
    float bias = ob[ct * 16 + c];
#pragma unroll
    for (int j = 0; j < 4; ++j) {
      int row = rt * 16 + g * 4 + j, col = ct * 16 + c;
      eig_f[row][col] = st[j] + bias + eig_f[row][col];
    }
  }
  __syncthreads();

  // LN2 -> hbf
  {
    int row = t >> 3, s = t & 7;
    float vals[16];
    float sum = 0.f;
#pragma unroll
    for (int k = 0; k < 16; ++k) {
      vals[k] = eig_f[row][s + 8 * k];
      sum += vals[k];
    }
    sum += __shfl_xor(sum, 1, 8);
    sum += __shfl_xor(sum, 2, 8);
    sum += __shfl_xor(sum, 4, 8);
    float mean = sum * (1.0f / 128.0f);
    float sq = 0.f;
#pragma unroll
    for (int k = 0; k < 16; ++k) {
      float d = vals[k] - mean;
      sq += d * d;
    }
    sq += __shfl_xor(sq, 1, 8);
    sq += __shfl_xor(sq, 2, 8);
    sq += __shfl_xor(sq, 4, 8);
    float rstd = rsqrtf(sq * (1.0f / 128.0f) + 1e-5f);
#pragma unroll
    for (int k = 0; k < 16; ++k) {
      int col = s + 8 * k;
      hbf[row][col] = f2bf((vals[k] - mean) * rstd * g2s[col] + g2b[col]);
    }
  }
  __syncthreads();

  // FFN1 + exact gelu -> attb (reuse)
#pragma unroll
  for (int i = 0; i < 4; ++i) {
    int ct = (w & 1) * 4 + i;
    f32x4 st = {0.f, 0.f, 0.f, 0.f};
#pragma unroll
    for (int kk = 0; kk < 8; ++kk) {
      s16x4 xf = *(const s16x4*)&hbf[rt * 16 + c][kk * 16 + g * 4];
      s16x4 yf = *(const s16x4*)&w1bf[(ct * 16 + c) * 128 + kk * 16 + g * 4];
      st = mfma16(xf, yf, st);
    }
    float bias = fb1[ct * 16 + c];
#pragma unroll
    for (int j = 0; j < 4; ++j) {
      float gv = st[j] + bias;
      attb[rt * 16 + g * 4 + j][ct * 16 + c] =
          f2bf(0.5f * gv * (1.0f + erff(gv * 0.7071067811865475f)));
    }
  }
  __syncthreads();

  // FFN2 + residual -> eig_f final
#pragma unroll
  for (int i = 0; i < 4; ++i) {
    int ct = (w & 1) * 4 + i;
    f32x4 st = {0.f, 0.f, 0.f, 0.f};
#pragma unroll
    for (int kk = 0; kk < 8; ++kk) {
      s16x4 xf = *(const s16x4*)&attb[rt * 16 + c][kk * 16 + g * 4];
      s16x4 yf = *(const s16x4*)&w2bf[(ct * 16 + c) * 128 + kk * 16 + g * 4];
      st = mfma16(xf, yf, st);
    }
    float bias = fb2[ct * 16 + c];
#pragma unroll
    for (int j = 0; j < 4; ++j) {
      int row = rt * 16 + g * 4 + j, col = ct * 16 + c;
      eig_f[row][col] = st[j] + bias + eig_f[row][col];
    }
  }
  __syncthreads();

#pragma unroll
  for (int p = 0; p < 4; ++p) {
    int idx = p * 256 + t;
    int row = idx >> 5, c4 = idx & 31;
    *(float4*)&eig[(size_t)(rows0 + row) * ND + c4 * 4] =
        *(const float4*)&eig_f[row][c4 * 4];
  }
}

// ---------- Kernel D: masked row-sum (pooling is linear in eig) ----------
__global__ __launch_bounds__(128) void kD(const float* __restrict__ eig,
                                          const int* __restrict__ length,
                                          float* __restrict__ rsum) {
  int b = blockIdx.x >> 4, c = blockIdx.x & 15, t = threadIdx.x;
  int len = length[b];
  int n0 = c * 64;
  float acc = 0.f;
  for (int i = 0; i < 64; ++i) {
    int n = n0 + i;
    if (n >= len) break;
    acc += eig[((size_t)b * NN + n) * ND + t];
  }
  rsum[(b * 16 + c) * ND + t] = acc;
}

// ---------- Kernel E: finish pooling + sigmoid + normalize coefficients ----------
__global__ __launch_bounds__(128) void kE(
    const float* __restrict__ rsum, const int* __restrict__ length,
    const float* __restrict__ dsW, const float* __restrict__ dsB,
    const float* __restrict__ dwW, const float* __restrict__ dwB,
    const float* __restrict__ dlW, const float* __restrict__ dlB,
    float* __restrict__ coe) {
  int b = blockIdx.x, t = threadIdx.x;
  __shared__ float s[128];
  __shared__ float pg[20];
  __shared__ float nrm[2];
  float a = 0.f;
#pragma unroll
  for (int c = 0; c < 16; ++c) a += rsum[(b * 16 + c) * ND + t];
  s[t] = a;
  __syncthreads();
  if (t < 20) {
    const float* W = t < 8 ? dsW + t * 128
                           : (t < 16 ? dwW + (t - 8) * 128 : dlW + (t - 16) * 128);
    float bias = t < 8 ? dsB[t] : (t < 16 ? dwB[t - 8] : dlB[t - 16]);
    float d = 0.f;
    for (int j = 0; j < 128; ++j) d += s[j] * W[j];
    float lf = (float)length[b];
    float pooled = (d + lf * bias) / (lf + 1e-8f);
    pg[t] = 1.f / (1.f + expf(-pooled));
  }
  __syncthreads();
  if (t == 0) {
    float a1 = 0.f, a2 = 0.f;
    for (int i = 0; i < 8; ++i) a1 += pg[i];
    for (int i = 8; i < 16; ++i) a2 += pg[i];
    nrm[0] = a1 + 1e-8f;
    nrm[1] = a2 + 1e-8f;
  }
  __syncthreads();
  if (t < 8) coe[b * 20 + t] = pg[t] / nrm[0];
  else if (t < 16) coe[b * 20 + t] = pg[t] / nrm[1];
  else if (t < 20) coe[b * 20 + t] = pg[t] * 2.0f;
}

// ---------- Kernel F: Chebyshev wave synthesis + tight frame ----------
__global__ __launch_bounds__(256) void k_wave(const float* __restrict__ eva,
                                              const float* __restrict__ coe,
                                              float* __restrict__ out) {
  int bn = blockIdx.x * 256 + threadIdx.x;
  int b = bn >> 10;
  float e = eva[bn];
  const float* cb = coe + b * 20;
  float y = e - 1.0f;
  float te = 1.0f, to = y;
  float cs = cb[0] * 0.5f * (1.0f - to);
#pragma unroll
  for (int i = 1; i < 8; ++i) {
    te = 2.f * y * to - te;
    to = 2.f * y * te - to;
    cs += cb[i] * 0.5f * (1.0f - to);
  }
  float cw[4];
#pragma unroll
  for (int j = 0; j < 4; ++j) {
    float fs = e * cb[16 + j];
    fs = (fs > 2.0f) ? 0.0f : fs;
    float yw = fs - 1.0f;
    float te2 = 1.0f, to2 = yw;
    float acc = 0.0f;
#pragma unroll
    for (int i = 1; i < 8; ++i) {
      te2 = 2.f * yw * to2 - te2;
      to2 = 2.f * yw * te2 - to2;
      acc += cb[8 + i] * 0.5f * (1.0f - te2);
    }
    cw[j] = acc;
  }
  float nrm = cs * cs + cw[0] * cw[0] + cw[1] * cw[1] + cw[2] * cw[2] +
              cw[3] * cw[3];
  float inv = 1.0f / (sqrtf(nrm) + 1e-8f);
  float* o = out + bn * 5;
  o[0] = cs * inv;
  o[1] = cw[0] * inv;
  o[2] = cw[1] * inv;
  o[3] = cw[2] * inv;
  o[4] = cw[3] * inv;
}

extern "C" void kernel_launch(void* const* d_in, const int* in_sizes, int n_in,
                              void* d_out, int out_size, void* d_ws,
                              size_t ws_size, hipStream_t stream) {
  const float* eva = (const float*)d_in[1];
  const int* length = (const int*)d_in[2];
  const float* eig_w_W = (const float*)d_in[3];
  const float* eig_w_b = (const float*)d_in[4];
  const float* ln1_s = (const float*)d_in[5];
  const float* ln1_b = (const float*)d_in[6];
  const float* ln2_s = (const float*)d_in[7];
  const float* ln2_b = (const float*)d_in[8];
  const float* qkv_W = (const float*)d_in[9];
  const float* qkv_b = (const float*)d_in[10];
  const float* out_W = (const float*)d_in[11];
  const float* out_b = (const float*)d_in[12];
  const float* ffn_W1 = (const float*)d_in[13];
  const float* ffn_b1 = (const float*)d_in[14];
  const float* ffn_W2 = (const float*)d_in[15];
  const float* ffn_b2 = (const float*)d_in[16];
  const float* dec_sca_W = (const float*)d_in[17];
  const float* dec_sca_b = (const float*)d_in[18];
  const float* dec_wav_W = (const float*)d_in[19];
  const float* dec_wav_b = (const float*)d_in[20];
  const float* dec_scl_W = (const float*)d_in[21];
  const float* dec_scl_b = (const float*)d_in[22];

  float* ws = (float*)d_ws;
  const size_t SZ = (size_t)NB * NN * ND;  // 2097152
  float* eig = ws;                         // f32 [16384][128]
  ushort* qg = (ushort*)(ws + SZ);         // bf16 [b,h,n,16]
  ushort* kg = qg + SZ;
  ushort* vg = kg + SZ;
  ushort* attg = vg + SZ;                  // bf16 [16384][128]
  float* rsum = (float*)(attg + SZ);       // [B*16*128]
  float* coe = rsum + NB * 16 * ND;        // [B*20]
  ushort* wbf = (ushort*)(coe + 512);      // bf16 weights, 116736 elems
  ushort* eWbf = wbf;
  ushort* qkvbf = wbf + 18432;
  ushort* outbf = wbf + 67584;
  ushort* w1bf = wbf + 83968;
  ushort* w2bf = wbf + 100352;

  kW<<<(116736 + 255) / 256, 256, 0, stream>>>(eig_w_W, qkv_W, out_W, ffn_W1,
                                               ffn_W2, wbf);
  kA<<<NB * NN / 32, 256, 0, stream>>>(eva, eWbf, eig_w_b, ln1_s, ln1_b, qkvbf,
                                       qkv_b, eig, qg, kg, vg);
  k_attn<<<NB * NH * 8, 512, 0, stream>>>(qg, kg, vg, length, attg);
  kB<<<NB * NN / 32, 256, 0, stream>>>(attg, outbf, out_b, ln2_s, ln2_b, w1bf,
                                       ffn_b1, w2bf, ffn_b2, eig);
  kD<<<NB * 16, 128, 0, stream>>>(eig, length, rsum);
  kE<<<NB, 128, 0, stream>>>(rsum, length, dec_sca_W, dec_sca_b, dec_wav_W,
                             dec_wav_b, dec_scl_W, dec_scl_b, coe);
  k_wave<<<(NB * NN) / 256, 256, 0, stream>>>(eva, coe, (float*)d_out);
}

// Round 9
// 99.612 us; speedup vs baseline: 12.5392x; 1.2844x over previous
//
#include <hip/hip_runtime.h>
#include <math.h>

#define NB 16
#define NN 1024
#define ND 128
#define NH 8
#define DH 16

typedef float f32x4 __attribute__((ext_vector_type(4)));
typedef short s16x4 __attribute__((ext_vector_type(4)));

static __device__ __forceinline__ ushort f2bf(float x) {
  unsigned u = __float_as_uint(x);
  u = (u + 0x7FFFu + ((u >> 16) & 1u)) >> 16;
  return (ushort)u;
}

// hardware 2^x (v_exp_f32); builtin so the hazard recognizer tracks it
static __device__ __forceinline__ float exp2h(float x) {
  return __builtin_amdgcn_exp2f(x);
}

// D[a][b] = sum_k X[a][k]*Y[b][k] + C.  X/Y frag: lane l holds row (l&15),
// k = 4*(l>>4)..+3.  D: lane l holds rows 4*(l>>4)+j (j=0..3), col l&15.
static __device__ __forceinline__ f32x4 mfma16(s16x4 a, s16x4 b, f32x4 c) {
  return __builtin_amdgcn_mfma_f32_16x16x16bf16_1k(a, b, c, 0, 0, 0);
}

// pack 4 f32 -> 4 bf16. NO inline asm: asm defs are invisible to the MFMA
// hazard recognizer (R4/R8 lesson: cvt_pk asm feeding MFMA -> NaN).
static __device__ __forceinline__ s16x4 pack_bf4(float p0, float p1, float p2,
                                                 float p3) {
  s16x4 r = {(short)f2bf(p0), (short)f2bf(p1), (short)f2bf(p2),
             (short)f2bf(p3)};
  return r;
}

#define QSCALE 0.36067376022224085f  // log2(e)/4, folded into Q at store

// ---------- Kernel W: one-time weight conversion to bf16 ----------
__global__ __launch_bounds__(256) void kW(
    const float* __restrict__ eW, const float* __restrict__ qkvW,
    const float* __restrict__ outW, const float* __restrict__ W1,
    const float* __restrict__ W2, ushort* __restrict__ wbf) {
  int i = blockIdx.x * 256 + threadIdx.x;
  if (i < 18432) {
    int r = i / 144, k = i - r * 144;
    wbf[i] = (k < 129) ? f2bf(eW[r * 129 + k]) : (ushort)0;
  } else if (i < 67584) {
    wbf[i] = f2bf(qkvW[i - 18432]);
  } else if (i < 83968) {
    wbf[i] = f2bf(outW[i - 67584]);
  } else if (i < 100352) {
    wbf[i] = f2bf(W1[i - 83968]);
  } else if (i < 116736) {
    wbf[i] = f2bf(W2[i - 100352]);
  }
}

// ---------- Kernel A: sine-enc + eig linear + LN1 + QKV, MFMA, 32 rows/block --
// qg: [b,h,n,16] bf16 pre-scaled by log2(e)/4; kg: [b,h,n,16]; vt: [b,h,d,n].
__global__ __launch_bounds__(256, 4) void kA(
    const float* __restrict__ eva, const ushort* __restrict__ eWbf,
    const float* __restrict__ eb, const float* __restrict__ g1s,
    const float* __restrict__ g1b, const ushort* __restrict__ qkvbf,
    const float* __restrict__ qb, float* __restrict__ eig,
    ushort* __restrict__ qg, ushort* __restrict__ kg,
    ushort* __restrict__ vt) {
  __shared__ __align__(16) ushort ee[32][148];
  __shared__ __align__(16) float eig_f[32][132];
  __shared__ __align__(16) ushort hbf[32][132];
  int t = threadIdx.x;
  int rows0 = blockIdx.x * 32;
  int w = t >> 6, l = t & 63, g = l >> 4, c = l & 15;

  // phase 1: ee = [eva, sin(pe), cos(pe)] bf16; div loop-invariant per thread
  {
    int d = t & 63, r0 = t >> 6;
    float div = __expf((float)(2 * d) * (-9.210340371976184f / 128.0f));
#pragma unroll
    for (int k = 0; k < 8; ++k) {
      int row = r0 + 4 * k;
      float e = eva[rows0 + row];
      float pe = e * 100.0f * div;
      ee[row][1 + d] = f2bf(__sinf(pe));
      ee[row][65 + d] = f2bf(__cosf(pe));
      if (d == 0) ee[row][0] = f2bf(e);
    }
  }
  for (int i = t; i < 32 * 19; i += 256) {
    int row = i / 19, cc = 129 + (i - row * 19);
    ee[row][cc] = 0;
  }
  __syncthreads();

  // phase 2: eig = ee @ eW^T + eb (K = 144)
  {
    int rt = w >> 1;
#pragma unroll
    for (int i = 0; i < 4; ++i) {
      int ct = (w & 1) * 4 + i;
      f32x4 st = {0.f, 0.f, 0.f, 0.f};
#pragma unroll
      for (int kk = 0; kk < 9; ++kk) {
        s16x4 xf = *(const s16x4*)&ee[rt * 16 + c][kk * 16 + g * 4];
        s16x4 yf = *(const s16x4*)&eWbf[(ct * 16 + c) * 144 + kk * 16 + g * 4];
        st = mfma16(xf, yf, st);
      }
      float bias = eb[ct * 16 + c];
#pragma unroll
      for (int j = 0; j < 4; ++j)
        eig_f[rt * 16 + g * 4 + j][ct * 16 + c] = st[j] + bias;
    }
  }
  __syncthreads();

  // eig residual out (f32, coalesced)
#pragma unroll
  for (int p = 0; p < 4; ++p) {
    int idx = p * 256 + t;
    int row = idx >> 5, c4 = idx & 31;
    *(float4*)&eig[(size_t)(rows0 + row) * ND + c4 * 4] =
        *(const float4*)&eig_f[row][c4 * 4];
  }

  // LN1 (8 lanes/row, stride-8 interleave)
  {
    int row = t >> 3, s = t & 7;
    float vals[16];
    float sum = 0.f;
#pragma unroll
    for (int k = 0; k < 16; ++k) {
      vals[k] = eig_f[row][s + 8 * k];
      sum += vals[k];
    }
    sum += __shfl_xor(sum, 1, 8);
    sum += __shfl_xor(sum, 2, 8);
    sum += __shfl_xor(sum, 4, 8);
    float mean = sum * (1.0f / 128.0f);
    float sq = 0.f;
#pragma unroll
    for (int k = 0; k < 16; ++k) {
      float d = vals[k] - mean;
      sq += d * d;
    }
    sq += __shfl_xor(sq, 1, 8);
    sq += __shfl_xor(sq, 2, 8);
    sq += __shfl_xor(sq, 4, 8);
    float rstd = rsqrtf(sq * (1.0f / 128.0f) + 1e-5f);
#pragma unroll
    for (int k = 0; k < 16; ++k) {
      int col = s + 8 * k;
      hbf[row][col] = f2bf((vals[k] - mean) * rstd * g1s[col] + g1b[col]);
    }
  }
  __syncthreads();

  // phase 3: QKV = h @ qkvW^T + qb; q scaled; v stored transposed
  {
    int rt = w >> 1;
    int b = rows0 >> 10, nn0 = rows0 & 1023;
#pragma unroll
    for (int i = 0; i < 12; ++i) {
      int ct = (w & 1) * 12 + i;
      f32x4 st = {0.f, 0.f, 0.f, 0.f};
#pragma unroll
      for (int kk = 0; kk < 8; ++kk) {
        s16x4 xf = *(const s16x4*)&hbf[rt * 16 + c][kk * 16 + g * 4];
        s16x4 yf = *(const s16x4*)&qkvbf[(ct * 16 + c) * 128 + kk * 16 + g * 4];
        st = mfma16(xf, yf, st);
      }
      float bias = qb[ct * 16 + c];
      int which = ct >> 3, head = ct & 7;
      if (which == 2) {
        // vt[((b*8+head)*16 + d=c)*1024 + n], n = nn0+rt*16+g*4+j consecutive
        unsigned lo = (unsigned)f2bf(st[0] + bias) |
                      ((unsigned)f2bf(st[1] + bias) << 16);
        unsigned hi = (unsigned)f2bf(st[2] + bias) |
                      ((unsigned)f2bf(st[3] + bias) << 16);
        uint2 pk;
        pk.x = lo;
        pk.y = hi;
        *(uint2*)(vt + ((size_t)(b * NH + head) * DH + c) * NN + nn0 +
                  rt * 16 + g * 4) = pk;
      } else {
        ushort* dst = which == 0 ? qg : kg;
        float sc = which == 0 ? QSCALE : 1.0f;
        size_t base =
            ((size_t)(b * NH + head) * NN + nn0 + rt * 16 + g * 4) * DH + c;
#pragma unroll
        for (int j = 0; j < 4; ++j)
          dst[base + j * DH] = f2bf((st[j] + bias) * sc);
      }
    }
  }
}

// ---------- Kernel C: MFMA attention v2 ----------
// full tiles checkless; V^T staged coalesced from pre-transposed global;
// p = exp2(S) with Q pre-scaled by log2(e)/4.
__global__ __launch_bounds__(512) void k_attn(
    const ushort* __restrict__ qg, const ushort* __restrict__ kg,
    const ushort* __restrict__ vt, const int* __restrict__ length,
    ushort* __restrict__ att) {
  __shared__ ushort Ksh[128][20];
  __shared__ ushort VTsh[16][136];
  int bid = blockIdx.x;
  int bh = bid >> 3, qc = bid & 7;
  int b = bh >> 3, h = bh & 7;
  int t = threadIdx.x;
  int w = t >> 6, l = t & 63, g = l >> 4, c = l & 15;
  int len = length[b];
  int qrow = qc * 128 + w * 16 + c;
  s16x4 qf = *(const s16x4*)(qg + ((size_t)bh * NN + qrow) * DH + g * 4);
  f32x4 oacc = {0.f, 0.f, 0.f, 0.f};
  float lsum = 0.f;
  int ksr = t >> 2, ksc = t & 3;
  int vr = t >> 5, vc = t & 31;
  const ushort* kbg = kg + (size_t)bh * NN * DH;
  const ushort* vbg = vt + (size_t)bh * DH * NN;
  for (int t0 = 0; t0 < len; t0 += 128) {
    // stage K [128][16] and V^T [16][128]; rows beyond len hold real (finite)
    // kA outputs and are masked in compute; all addresses in-bounds.
    *(uint2*)&Ksh[ksr][ksc * 4] =
        *(const uint2*)(kbg + (size_t)(t0 + ksr) * DH + ksc * 4);
    *(uint2*)&VTsh[vr][vc * 4] =
        *(const uint2*)(vbg + (size_t)vr * NN + t0 + vc * 4);
    __syncthreads();
    if (t0 + 128 <= len) {
#pragma unroll
      for (int kt = 0; kt < 8; ++kt) {
        s16x4 kf = *(const s16x4*)&Ksh[kt * 16 + c][g * 4];
        f32x4 st = {0.f, 0.f, 0.f, 0.f};
        st = mfma16(kf, qf, st);
        float p0 = exp2h(st[0]), p1 = exp2h(st[1]);
        float p2 = exp2h(st[2]), p3 = exp2h(st[3]);
        lsum += (p0 + p1) + (p2 + p3);
        s16x4 pf = pack_bf4(p0, p1, p2, p3);
        s16x4 vf = *(const s16x4*)&VTsh[c][kt * 16 + g * 4];
        oacc = mfma16(vf, pf, oacc);
      }
    } else {
      for (int kt = 0; kt < 8 && t0 + kt * 16 < len; ++kt) {
        s16x4 kf = *(const s16x4*)&Ksh[kt * 16 + c][g * 4];
        f32x4 st = {0.f, 0.f, 0.f, 0.f};
        st = mfma16(kf, qf, st);
        int kj = t0 + kt * 16 + g * 4;
        float p0 = (kj + 0 < len) ? exp2h(st[0]) : 0.f;
        float p1 = (kj + 1 < len) ? exp2h(st[1]) : 0.f;
        float p2 = (kj + 2 < len) ? exp2h(st[2]) : 0.f;
        float p3 = (kj + 3 < len) ? exp2h(st[3]) : 0.f;
        lsum += (p0 + p1) + (p2 + p3);
        s16x4 pf = pack_bf4(p0, p1, p2, p3);
        s16x4 vf = *(const s16x4*)&VTsh[c][kt * 16 + g * 4];
        oacc = mfma16(vf, pf, oacc);
      }
    }
    __syncthreads();
  }
  lsum += __shfl_xor(lsum, 16, 64);
  lsum += __shfl_xor(lsum, 32, 64);
  float inv = 1.0f / lsum;
  s16x4 ob = pack_bf4(oacc[0] * inv, oacc[1] * inv, oacc[2] * inv,
                      oacc[3] * inv);
  *(s16x4*)(att + ((size_t)b * NN + qrow) * ND + h * DH + g * 4) = ob;
}

// ---------- Kernel B: outproj + residual + LN2 + FFN + pooled colsum ----------
__global__ __launch_bounds__(256, 4) void kB(
    const ushort* __restrict__ attg, const ushort* __restrict__ outbf,
    const float* __restrict__ ob, const float* __restrict__ g2s,
    const float* __restrict__ g2b, const ushort* __restrict__ w1bf,
    const float* __restrict__ fb1, const ushort* __restrict__ w2bf,
    const float* __restrict__ fb2, const float* __restrict__ eig,
    const int* __restrict__ length, float* __restrict__ bsum) {
  __shared__ __align__(16) ushort attb[32][136];
  __shared__ __align__(16) float eig_f[32][132];
  __shared__ __align__(16) ushort hbf[32][132];
  __shared__ float csum[2][128];
  int t = threadIdx.x;
  int rows0 = blockIdx.x * 32;
  int w = t >> 6, l = t & 63, g = l >> 4, c = l & 15;
  int rt = w >> 1;

#pragma unroll
  for (int p = 0; p < 2; ++p) {
    int idx = p * 256 + t;
    int row = idx >> 4, c8 = idx & 15;
    *(uint4*)&attb[row][c8 * 8] =
        *(const uint4*)&attg[(size_t)(rows0 + row) * ND + c8 * 8];
  }
#pragma unroll
  for (int p = 0; p < 4; ++p) {
    int idx = p * 256 + t;
    int row = idx >> 5, c4 = idx & 31;
    *(float4*)&eig_f[row][c4 * 4] =
        *(const float4*)&eig[(size_t)(rows0 + row) * ND + c4 * 4];
  }
  __syncthreads();

  // outproj + residual
#pragma unroll
  for (int i = 0; i < 4; ++i) {
    int ct = (w & 1) * 4 + i;
    f32x4 st = {0.f, 0.f, 0.f, 0.f};
#pragma unroll
    for (int kk = 0; kk < 8; ++kk) {
      s16x4 xf = *(const s16x4*)&attb[rt * 16 + c][kk * 16 + g * 4];
      s16x4 yf = *(const s16x4*)&outbf[(ct * 16 + c) * 128 + kk * 16 + g * 4];
      st = mfma16(xf, yf, st);
    }
    float bias = ob[ct * 16 + c];
#pragma unroll
    for (int j = 0; j < 4; ++j) {
      int row = rt * 16 + g * 4 + j, col = ct * 16 + c;
      eig_f[row][col] = st[j] + bias + eig_f[row][col];
    }
  }
  __syncthreads();

  // LN2
  {
    int row = t >> 3, s = t & 7;
    float vals[16];
    float sum = 0.f;
#pragma unroll
    for (int k = 0; k < 16; ++k) {
      vals[k] = eig_f[row][s + 8 * k];
      sum += vals[k];
    }
    sum += __shfl_xor(sum, 1, 8);
    sum += __shfl_xor(sum, 2, 8);
    sum += __shfl_xor(sum, 4, 8);
    float mean = sum * (1.0f / 128.0f);
    float sq = 0.f;
#pragma unroll
    for (int k = 0; k < 16; ++k) {
      float d = vals[k] - mean;
      sq += d * d;
    }
    sq += __shfl_xor(sq, 1, 8);
    sq += __shfl_xor(sq, 2, 8);
    sq += __shfl_xor(sq, 4, 8);
    float rstd = rsqrtf(sq * (1.0f / 128.0f) + 1e-5f);
#pragma unroll
    for (int k = 0; k < 16; ++k) {
      int col = s + 8 * k;
      hbf[row][col] = f2bf((vals[k] - mean) * rstd * g2s[col] + g2b[col]);
    }
  }
  __syncthreads();

  // FFN1 + exact gelu -> attb
#pragma unroll
  for (int i = 0; i < 4; ++i) {
    int ct = (w & 1) * 4 + i;
    f32x4 st = {0.f, 0.f, 0.f, 0.f};
#pragma unroll
    for (int kk = 0; kk < 8; ++kk) {
      s16x4 xf = *(const s16x4*)&hbf[rt * 16 + c][kk * 16 + g * 4];
      s16x4 yf = *(const s16x4*)&w1bf[(ct * 16 + c) * 128 + kk * 16 + g * 4];
      st = mfma16(xf, yf, st);
    }
    float bias = fb1[ct * 16 + c];
#pragma unroll
    for (int j = 0; j < 4; ++j) {
      float gv = st[j] + bias;
      attb[rt * 16 + g * 4 + j][ct * 16 + c] =
          f2bf(0.5f * gv * (1.0f + erff(gv * 0.7071067811865475f)));
    }
  }
  __syncthreads();

  // FFN2 + residual
#pragma unroll
  for (int i = 0; i < 4; ++i) {
    int ct = (w & 1) * 4 + i;
    f32x4 st = {0.f, 0.f, 0.f, 0.f};
#pragma unroll
    for (int kk = 0; kk < 8; ++kk) {
      s16x4 xf = *(const s16x4*)&attb[rt * 16 + c][kk * 16 + g * 4];
      s16x4 yf = *(const s16x4*)&w2bf[(ct * 16 + c) * 128 + kk * 16 + g * 4];
      st = mfma16(xf, yf, st);
    }
    float bias = fb2[ct * 16 + c];
#pragma unroll
    for (int j = 0; j < 4; ++j) {
      int row = rt * 16 + g * 4 + j, col = ct * 16 + c;
      eig_f[row][col] = st[j] + bias + eig_f[row][col];
    }
  }
  __syncthreads();

  // masked column-sum of final eig rows (pooling is linear; eig never
  // round-trips to global)
  {
    int b = rows0 >> 10, n0 = rows0 & 1023;
    int len = length[b];
    int col = t & 127, half = t >> 7;
    float s = 0.f;
#pragma unroll
    for (int r = 0; r < 16; ++r) {
      int row = half * 16 + r;
      if (n0 + row < len) s += eig_f[row][col];
    }
    csum[half][col] = s;
  }
  __syncthreads();
  if (t < 128) bsum[(size_t)blockIdx.x * 128 + t] = csum[0][t] + csum[1][t];
}

// ---------- Kernel E: finish pooling + sigmoid + normalize coefficients ------
__global__ __launch_bounds__(128) void kE(
    const float* __restrict__ bsum, const int* __restrict__ length,
    const float* __restrict__ dsW, const float* __restrict__ dsB,
    const float* __restrict__ dwW, const float* __restrict__ dwB,
    const float* __restrict__ dlW, const float* __restrict__ dlB,
    float* __restrict__ coe) {
  int b = blockIdx.x, t = threadIdx.x;
  __shared__ float s[128];
  __shared__ float pg[20];
  __shared__ float nrm[2];
  float a = 0.f;
#pragma unroll
  for (int c = 0; c < 32; ++c) a += bsum[(size_t)(b * 32 + c) * 128 + t];
  s[t] = a;
  __syncthreads();
  if (t < 20) {
    const float* W = t < 8 ? dsW + t * 128
                           : (t < 16 ? dwW + (t - 8) * 128 : dlW + (t - 16) * 128);
    float bias = t < 8 ? dsB[t] : (t < 16 ? dwB[t - 8] : dlB[t - 16]);
    float d = 0.f;
    for (int j = 0; j < 128; ++j) d += s[j] * W[j];
    float lf = (float)length[b];
    float pooled = (d + lf * bias) / (lf + 1e-8f);
    pg[t] = 1.f / (1.f + expf(-pooled));
  }
  __syncthreads();
  if (t == 0) {
    float a1 = 0.f, a2 = 0.f;
    for (int i = 0; i < 8; ++i) a1 += pg[i];
    for (int i = 8; i < 16; ++i) a2 += pg[i];
    nrm[0] = a1 + 1e-8f;
    nrm[1] = a2 + 1e-8f;
  }
  __syncthreads();
  if (t < 8) coe[b * 20 + t] = pg[t] / nrm[0];
  else if (t < 16) coe[b * 20 + t] = pg[t] / nrm[1];
  else if (t < 20) coe[b * 20 + t] = pg[t] * 2.0f;
}

// ---------- Kernel F: Chebyshev wave synthesis + tight frame ----------
__global__ __launch_bounds__(256) void k_wave(const float* __restrict__ eva,
                                              const float* __restrict__ coe,
                                              float* __restrict__ out) {
  int bn = blockIdx.x * 256 + threadIdx.x;
  int b = bn >> 10;
  float e = eva[bn];
  const float* cb = coe + b * 20;
  float y = e - 1.0f;
  float te = 1.0f, to = y;
  float cs = cb[0] * 0.5f * (1.0f - to);
#pragma unroll
  for (int i = 1; i < 8; ++i) {
    te = 2.f * y * to - te;
    to = 2.f * y * te - to;
    cs += cb[i] * 0.5f * (1.0f - to);
  }
  float cw[4];
#pragma unroll
  for (int j = 0; j < 4; ++j) {
    float fs = e * cb[16 + j];
    fs = (fs > 2.0f) ? 0.0f : fs;
    float yw = fs - 1.0f;
    float te2 = 1.0f, to2 = yw;
    float acc = 0.0f;
#pragma unroll
    for (int i = 1; i < 8; ++i) {
      te2 = 2.f * yw * to2 - te2;
      to2 = 2.f * yw * te2 - to2;
      acc += cb[8 + i] * 0.5f * (1.0f - te2);
    }
    cw[j] = acc;
  }
  float nrm = cs * cs + cw[0] * cw[0] + cw[1] * cw[1] + cw[2] * cw[2] +
              cw[3] * cw[3];
  float inv = 1.0f / (sqrtf(nrm) + 1e-8f);
  float* o = out + bn * 5;
  o[0] = cs * inv;
  o[1] = cw[0] * inv;
  o[2] = cw[1] * inv;
  o[3] = cw[2] * inv;
  o[4] = cw[3] * inv;
}

extern "C" void kernel_launch(void* const* d_in, const int* in_sizes, int n_in,
                              void* d_out, int out_size, void* d_ws,
                              size_t ws_size, hipStream_t stream) {
  const float* eva = (const float*)d_in[1];
  const int* length = (const int*)d_in[2];
  const float* eig_w_W = (const float*)d_in[3];
  const float* eig_w_b = (const float*)d_in[4];
  const float* ln1_s = (const float*)d_in[5];
  const float* ln1_b = (const float*)d_in[6];
  const float* ln2_s = (const float*)d_in[7];
  const float* ln2_b = (const float*)d_in[8];
  const float* qkv_W = (const float*)d_in[9];
  const float* qkv_b = (const float*)d_in[10];
  const float* out_W = (const float*)d_in[11];
  const float* out_b = (const float*)d_in[12];
  const float* ffn_W1 = (const float*)d_in[13];
  const float* ffn_b1 = (const float*)d_in[14];
  const float* ffn_W2 = (const float*)d_in[15];
  const float* ffn_b2 = (const float*)d_in[16];
  const float* dec_sca_W = (const float*)d_in[17];
  const float* dec_sca_b = (const float*)d_in[18];
  const float* dec_wav_W = (const float*)d_in[19];
  const float* dec_wav_b = (const float*)d_in[20];
  const float* dec_scl_W = (const float*)d_in[21];
  const float* dec_scl_b = (const float*)d_in[22];

  float* ws = (float*)d_ws;
  const size_t SZ = (size_t)NB * NN * ND;  // 2097152
  float* eig = ws;                         // f32 [16384][128]
  ushort* qg = (ushort*)(ws + SZ);         // bf16 [b,h,n,16] (scaled)
  ushort* kg = qg + SZ;                    // bf16 [b,h,n,16]
  ushort* vt = kg + SZ;                    // bf16 [b,h,d,n]
  ushort* attg = vt + SZ;                  // bf16 [16384][128]
  float* bsum = (float*)(attg + SZ);       // f32 [512][128]
  float* coe = bsum + 512 * 128;           // [B*20]
  ushort* wbf = (ushort*)(coe + 512);      // bf16 weights
  ushort* eWbf = wbf;
  ushort* qkvbf = wbf + 18432;
  ushort* outbf = wbf + 67584;
  ushort* w1bf = wbf + 83968;
  ushort* w2bf = wbf + 100352;

  kW<<<(116736 + 255) / 256, 256, 0, stream>>>(eig_w_W, qkv_W, out_W, ffn_W1,
                                               ffn_W2, wbf);
  kA<<<NB * NN / 32, 256, 0, stream>>>(eva, eWbf, eig_w_b, ln1_s, ln1_b, qkvbf,
                                       qkv_b, eig, qg, kg, vt);
  k_attn<<<NB * NH * 8, 512, 0, stream>>>(qg, kg, vt, length, attg);
  kB<<<NB * NN / 32, 256, 0, stream>>>(attg, outbf, out_b, ln2_s, ln2_b, w1bf,
                                       ffn_b1, w2bf, ffn_b2, eig, length, bsum);
  kE<<<NB, 128, 0, stream>>>(bsum, length, dec_sca_W, dec_sca_b, dec_wav_W,
                             dec_wav_b, dec_scl_W, dec_scl_b, coe);
  k_wave<<<(NB * NN) / 256, 256, 0, stream>>>(eva, coe, (float*)d_out);
}